// Round 14
// baseline (593.907 us; speedup 1.0000x reference)
//
#include <hip/hip_runtime.h>
#include <hip/hip_bf16.h>
#include <math.h>

#define N_NODES 80000
#define N_EDGES 1280000
#define NCB 64
#define CB_DIV 1250                 // coarse bucket = dst / 1250 -> 0..63
#define CB_CAP 21000                // mean 20000
#define NFB 1250                    // fine bucket = dst >> 6 (64 nodes each)
#define FB_CAP 1280                 // mean 1024, sigma ~32
#define EPB 1280                    // edges per k_part block (grid 1000)
#define SPB 10                      // max strips (128 edges) per fine bucket

typedef __hip_bfloat16 bf16;

__device__ __forceinline__ float leaky(float x) { return x >= 0.f ? x : 0.01f * x; }

// ---------------- setup kernels ----------------

__global__ void k_zero(int* deg, float* bnsums, int* ctails, int* ftails) {
    int i = blockIdx.x * blockDim.x + threadIdx.x;
    if (i < N_NODES) deg[i] = 0;
    if (i < 384) bnsums[i] = 0.f;
    if (i < NCB) ctails[i] = 0;
    if (i < NFB) ftails[i] = 0;
}

// pass 1: 64-way coarse bin of (src,dst) pairs; block bulk-reserves regions,
// writes ~20-edge runs (coalesced-ish). No random scatter, no deg atomics.
__global__ void __launch_bounds__(256)
k_part(const int* __restrict__ ei, int2* __restrict__ cpairs,
       int* __restrict__ ctails) {
    __shared__ int cnt[NCB], off[NCB];
    int t = threadIdx.x;
    if (t < NCB) cnt[t] = 0;
    __syncthreads();
    int base = blockIdx.x * EPB;
    int2 loc[5];
#pragma unroll
    for (int u = 0; u < 5; ++u) {
        int e = base + u * 256 + t;
        int s = ei[e], d = ei[N_EDGES + e];
        loc[u] = make_int2(s, d);
        atomicAdd(&cnt[d / CB_DIV], 1);
    }
    __syncthreads();
    if (t < NCB) off[t] = atomicAdd(&ctails[t], cnt[t]);
    __syncthreads();
#pragma unroll
    for (int u = 0; u < 5; ++u) {
        int b = loc[u].y / CB_DIV;
        int pos = atomicAdd(&off[b], 1);
        cpairs[(size_t)b * CB_CAP + pos] = loc[u];
    }
}

// deg counting, bucket-pinned (atomics confined to a 5 KB dst slice per bucket).
__global__ void __launch_bounds__(256)
k_deg_bkt(const int2* __restrict__ cpairs, const int* __restrict__ ctails,
          int* __restrict__ deg) {
    int bucket = blockIdx.x & 63;
    int jb = blockIdx.x >> 6;
    int nb = gridDim.x >> 6;
    int cnt = ctails[bucket];
    const int2* lst = cpairs + (size_t)bucket * CB_CAP;
    for (int i = jb * 256 + threadIdx.x; i < cnt; i += nb * 256)
        atomicAdd(&deg[lst[i].y], 1);
}

// pass 2: refine coarse bucket -> fine buckets of 64 nodes. LDS-staged strip,
// <=21 fine bins per coarse bucket, ~100-edge runs. Record: src | (dst&63)<<20.
__global__ void __launch_bounds__(256)
k_refine(const int2* __restrict__ cpairs, const int* __restrict__ ctails,
         int* __restrict__ ftails, unsigned int* __restrict__ fpairs) {
    __shared__ int2 s_ed[2048];  // 16 KB strip stage
    __shared__ int cnt2[32], off2[32];
    int b = blockIdx.x & 63;
    int j = blockIdx.x >> 6;
    int t = threadIdx.x;
    int cnt = ctails[b];
    int s0 = j * 2048;
    if (s0 >= cnt) return;
    int n = min(2048, cnt - s0);
    int fb0 = (b * CB_DIV) >> 6;
    int nbins = (((b + 1) * CB_DIV - 1) >> 6) - fb0 + 1;  // <= 21
    const int2* lst = cpairs + (size_t)b * CB_CAP + s0;
    for (int i = t; i < n; i += 256) s_ed[i] = lst[i];
    if (t < 32) cnt2[t] = 0;
    __syncthreads();
    for (int i = t; i < n; i += 256)
        atomicAdd(&cnt2[(s_ed[i].y >> 6) - fb0], 1);
    __syncthreads();
    if (t < nbins && cnt2[t] > 0) off2[t] = atomicAdd(&ftails[fb0 + t], cnt2[t]);
    __syncthreads();
    for (int i = t; i < n; i += 256) {
        int2 pr = s_ed[i];
        int fbl = (pr.y >> 6) - fb0;
        int pos = atomicAdd(&off2[fbl], 1);
        fpairs[(size_t)(fb0 + fbl) * FB_CAP + pos] =
            (unsigned int)pr.x | ((unsigned int)(pr.y & 63) << 20);
    }
}

// pass 3: per-fine-bucket LDS counting sort by 6-bit dst-local key.
// All reads/writes confined to a 5 KB region owned by one CU -> full merging.
__global__ void __launch_bounds__(256)
k_sortfine(const unsigned int* __restrict__ fpairs, const int* __restrict__ ftails,
           unsigned int* __restrict__ srt) {
    __shared__ unsigned int stage[FB_CAP];
    __shared__ int hist[64], cur[64];
    int fb = blockIdx.x;
    int t = threadIdx.x;
    int cnt = ftails[fb];
    const unsigned int* lst = fpairs + (size_t)fb * FB_CAP;
    if (t < 64) hist[t] = 0;
    __syncthreads();
    for (int i = t; i < cnt; i += 256) {
        unsigned int r = lst[i];
        stage[i] = r;
        atomicAdd(&hist[r >> 20], 1);
    }
    __syncthreads();
    if (t == 0) {
        int s = 0;
        for (int j = 0; j < 64; ++j) { cur[j] = s; s += hist[j]; }
    }
    __syncthreads();
    unsigned int* dstp = srt + (size_t)fb * FB_CAP;
    for (int i = t; i < cnt; i += 256) {
        unsigned int r = stage[i];
        int p = atomicAdd(&cur[r >> 20], 1);
        dstp[p] = r;
    }
}

__global__ void k_dinv(const int* __restrict__ deg, float* __restrict__ dinv) {
    int i = blockIdx.x * blockDim.x + threadIdx.x;
    if (i < N_NODES) dinv[i] = rsqrtf((float)deg[i] + 2.0f);  // + self-loop weight 2
}

// h0 = x @ W0; hs = bf16(dinv*h0)  (pre-scaled gather rows)
__global__ void k_h0s(const float* __restrict__ x, const float* __restrict__ W0,
                      const float* __restrict__ dinv, bf16* __restrict__ hs) {
    int tid = blockIdx.x * blockDim.x + threadIdx.x;
    if (tid < N_NODES * 64) {
        int v = tid >> 6, c = tid & 63;
        float x0 = x[v * 3], x1 = x[v * 3 + 1], x2 = x[v * 3 + 2];
        float h = x0 * W0[c] + x1 * W0[64 + c] + x2 * W0[128 + c];
        hs[tid] = __float2bfloat16(dinv[v] * h);
    }
}

// ---------------- per-stage kernels ----------------

// segmented aggregation over SORTED fine-bucket lists (R10 register shape).
// Wave = 128-edge strip of one bucket; carried dst-local via readfirstlane;
// interior segments -> plain store; strip-straddling -> atomicAdd (~2/strip).
// yagg must be zero-initialized.
__global__ void __launch_bounds__(256)
k_agg_srt(const bf16* __restrict__ hs, const unsigned int* __restrict__ srt,
          const int* __restrict__ ftails, float* __restrict__ yagg) {
    int lane = threadIdx.x & 63;
    int wid = (blockIdx.x * blockDim.x + threadIdx.x) >> 6;
    int fb = wid / SPB, strip = wid % SPB;
    if (fb >= NFB) return;
    int cnt = ftails[fb];
    int e0 = strip * 128;
    if (e0 >= cnt) return;
    int n = min(128, cnt - e0);
    const unsigned int* lst = srt + (size_t)fb * FB_CAP + e0;
    size_t nbase = (size_t)fb * 64;
    float acc = 0.f;
    bool lead = (e0 > 0);   // first segment may extend into previous strip
    unsigned int r[8];
#pragma unroll
    for (int u = 0; u < 8; ++u) r[u] = lst[u];  // padded alloc: safe
    int cur = __builtin_amdgcn_readfirstlane((int)(r[0] >> 20));
    int nb = (n + 7) >> 3;
    int e = 0;
    for (int b = 0; b < nb; ++b) {
        int mlim = n - e;  // wave-uniform
        float pv[8];
#pragma unroll
        for (int u = 0; u < 8; ++u) {
            if (u < mlim)
                pv[u] = __bfloat162float(hs[(size_t)(r[u] & 0xFFFFFu) * 64 + lane]);
        }
        unsigned int rn[8];
        if (b + 1 < nb) {
#pragma unroll
            for (int u = 0; u < 8; ++u) rn[u] = lst[e + 8 + u];
        }
#pragma unroll
        for (int u = 0; u < 8; ++u) {
            if (u < mlim) {
                int dl = __builtin_amdgcn_readfirstlane((int)(r[u] >> 20));
                if (dl != cur) {
                    if (lead) {
                        atomicAdd(&yagg[(nbase + cur) * 64 + lane], acc);
                        lead = false;
                    } else {
                        yagg[(nbase + cur) * 64 + lane] = acc;  // exclusive owner
                    }
                    acc = 0.f;
                    cur = dl;
                }
                acc += pv[u];
            }
        }
        e += 8;
        if (b + 1 < nb) {
#pragma unroll
            for (int u = 0; u < 8; ++u) r[u] = rn[u];
        }
    }
    bool more = (e0 + n < cnt);  // later strips exist -> trailing may be shared
    if (lead || more) atomicAdd(&yagg[(nbase + cur) * 64 + lane], acc);
    else yagg[(nbase + cur) * 64 + lane] = acc;
}

// per-channel sum/sumsq of y_final = dinv[v]*(yagg + 2*hs_self) + bias[c]
__global__ void __launch_bounds__(256)
k_bnstats(const float* __restrict__ yagg, const bf16* __restrict__ hs,
          const float* __restrict__ dinv, const float* __restrict__ bias,
          float* __restrict__ bnsum) {
    int tid = blockIdx.x * blockDim.x + threadIdx.x;
    int stride = gridDim.x * blockDim.x;  // multiple of 64 -> lane == channel
    float bc = bias[tid & 63];
    float bs = 0.f, bss = 0.f;
    for (size_t i = tid; i < (size_t)N_NODES * 64; i += stride) {
        float comb = yagg[i] + 2.f * __bfloat162float(hs[i]);
        float yf = dinv[i >> 6] * comb + bc;
        bs += yf;
        bss += yf * yf;
    }
    __shared__ float s1[256], s2[256];
    s1[threadIdx.x] = bs;
    s2[threadIdx.x] = bss;
    __syncthreads();
    if (threadIdx.x < 64) {
        float t1 = s1[threadIdx.x] + s1[threadIdx.x + 64] + s1[threadIdx.x + 128] + s1[threadIdx.x + 192];
        float t2 = s2[threadIdx.x] + s2[threadIdx.x + 64] + s2[threadIdx.x + 128] + s2[threadIdx.x + 192];
        atomicAdd(&bnsum[threadIdx.x], t1);
        atomicAdd(&bnsum[64 + threadIdx.x], t2);
    }
}

// BN + maxpool + leaky + (a@lw.T+lb) + leaky + second matmul, register-tiled.
// Phase 1 input: y_final = dinv*(yagg + 2*hs_self) + bias (bias folded into BN shift).
// MODE 0: phase3 = o @ Wn (64x64) -> hs_next = bf16(dinv*hn).
// MODE 1: phase3 = o @ Wn (64x3)  -> hs3 = float4(dinv*h3).
template <int P, int MODE>
__global__ void __launch_bounds__(128)
k_post64(const float* __restrict__ yagg, const bf16* __restrict__ hs,
         const float* __restrict__ dinv, const float* __restrict__ bias,
         const float* __restrict__ bnsum,
         const float* __restrict__ g, const float* __restrict__ bb,
         const float* __restrict__ lw, const float* __restrict__ lb,
         const float* __restrict__ Wn, bf16* __restrict__ hsout,
         float4* __restrict__ hs3) {
    __shared__ float s_aT[2][64 * 36];  // per-wave activation tile (transposed), reused as oT
    __shared__ float s_lwT[64 * 64];    // lw transposed: [k][c]
    __shared__ float s_Wn[MODE == 0 ? 64 * 64 : 64 * 3];
    int t = threadIdx.x;
    int w = t >> 6, lane = t & 63;
    for (int k0 = t; k0 < 4096; k0 += 128) {
        int kk = k0 >> 6, cc = k0 & 63;
        s_lwT[kk * 64 + cc] = lw[cc * 64 + kk];
        if (MODE == 0) s_Wn[k0] = Wn[k0];
    }
    if (MODE == 1) {
        for (int i = t; i < 64 * 3; i += 128) s_Wn[i] = Wn[i];
    }
    float inv_n = 1.0f / (float)N_NODES;
    float mean = bnsum[lane] * inv_n;
    float var = fmaxf(bnsum[64 + lane] * inv_n - mean * mean, 0.f);
    float sc = g[lane] * rsqrtf(var + 1e-5f);
    float sh = bb[lane] - mean * sc;
    float shb = fmaf(sc, bias[lane], sh);  // folds GCN bias into BN shift
    int c0 = (lane >> 3) * 8, n0 = (lane & 7) * 4;
    float lbv[8];
#pragma unroll
    for (int i = 0; i < 8; ++i) lbv[i] = lb[c0 + i];
    float* aT = s_aT[w];

    for (int tile = blockIdx.x; tile < N_NODES / 64; tile += gridDim.x) {
        int nbase = tile * 64 + w * 32;
        __syncthreads();  // also covers initial weight-fill -> first use
#pragma unroll 4
        for (int i = 0; i < 32; ++i) {
            size_t idx = (size_t)(nbase + i) * 64 + lane;
            float comb = yagg[idx] + 2.f * __bfloat162float(hs[idx]);
            float z = fmaf(sc * dinv[nbase + i], comb, shb);
            float m = z;
#pragma unroll
            for (int d = 1; d <= P; ++d) {
                float up = __shfl(z, lane + d);
                float dn = __shfl(z, lane - d);
                m = fmaxf(m, (lane + d < 64) ? up : -INFINITY);
                m = fmaxf(m, (lane - d >= 0) ? dn : -INFINITY);
            }
            aT[lane * 36 + i] = leaky(m);
        }
        __syncthreads();
        // phase 2: o = leaky(a @ lw.T + lb)
        float acc[4][8];
#pragma unroll
        for (int nn = 0; nn < 4; ++nn)
#pragma unroll
            for (int i = 0; i < 8; ++i) acc[nn][i] = lbv[i];
#pragma unroll 8
        for (int k = 0; k < 64; ++k) {
            float4 av = *(const float4*)&aT[k * 36 + n0];
            float4 w0 = *(const float4*)&s_lwT[k * 64 + c0];
            float4 w1 = *(const float4*)&s_lwT[k * 64 + c0 + 4];
            float a4[4] = {av.x, av.y, av.z, av.w};
            float wv[8] = {w0.x, w0.y, w0.z, w0.w, w1.x, w1.y, w1.z, w1.w};
#pragma unroll
            for (int nn = 0; nn < 4; ++nn)
#pragma unroll
                for (int i = 0; i < 8; ++i) acc[nn][i] = fmaf(a4[nn], wv[i], acc[nn][i]);
        }
#pragma unroll
        for (int nn = 0; nn < 4; ++nn)
#pragma unroll
            for (int i = 0; i < 8; ++i) acc[nn][i] = leaky(acc[nn][i]);

        // write oT (aliases aT; same-wave LDS program order is safe)
#pragma unroll
        for (int i = 0; i < 8; ++i) {
            float4 ov = make_float4(acc[0][i], acc[1][i], acc[2][i], acc[3][i]);
            *(float4*)&aT[(c0 + i) * 36 + n0] = ov;
        }
        if (MODE == 0) {
            float acc2[4][8];
#pragma unroll
            for (int nn = 0; nn < 4; ++nn)
#pragma unroll
                for (int i = 0; i < 8; ++i) acc2[nn][i] = 0.f;
#pragma unroll 8
            for (int k = 0; k < 64; ++k) {
                float4 av = *(const float4*)&aT[k * 36 + n0];
                float4 w0 = *(const float4*)&s_Wn[k * 64 + c0];
                float4 w1 = *(const float4*)&s_Wn[k * 64 + c0 + 4];
                float a4[4] = {av.x, av.y, av.z, av.w};
                float wv[8] = {w0.x, w0.y, w0.z, w0.w, w1.x, w1.y, w1.z, w1.w};
#pragma unroll
                for (int nn = 0; nn < 4; ++nn)
#pragma unroll
                    for (int i = 0; i < 8; ++i) acc2[nn][i] = fmaf(a4[nn], wv[i], acc2[nn][i]);
            }
#pragma unroll
            for (int nn = 0; nn < 4; ++nn) {
                int node = nbase + n0 + nn;
                float dv = dinv[node];
                bf16 pk[8];
#pragma unroll
                for (int i = 0; i < 8; ++i) pk[i] = __float2bfloat16(dv * acc2[nn][i]);
                *(uint4*)&hsout[(size_t)node * 64 + c0] = *(uint4*)pk;
            }
        } else {
            // proj fused: h3 = o @ w2 (64x3); 8 lanes duplicate, c0==0 writes
            float acc3[4][3];
#pragma unroll
            for (int nn = 0; nn < 4; ++nn)
#pragma unroll
                for (int j = 0; j < 3; ++j) acc3[nn][j] = 0.f;
#pragma unroll 8
            for (int k = 0; k < 64; ++k) {
                float4 av = *(const float4*)&aT[k * 36 + n0];
                float a4[4] = {av.x, av.y, av.z, av.w};
                float w0 = s_Wn[k * 3 + 0], w1 = s_Wn[k * 3 + 1], w2v = s_Wn[k * 3 + 2];
#pragma unroll
                for (int nn = 0; nn < 4; ++nn) {
                    acc3[nn][0] = fmaf(a4[nn], w0, acc3[nn][0]);
                    acc3[nn][1] = fmaf(a4[nn], w1, acc3[nn][1]);
                    acc3[nn][2] = fmaf(a4[nn], w2v, acc3[nn][2]);
                }
            }
            if (c0 == 0) {
#pragma unroll
                for (int nn = 0; nn < 4; ++nn) {
                    int node = nbase + n0 + nn;
                    float dv = dinv[node];
                    hs3[node] = make_float4(dv * acc3[nn][0], dv * acc3[nn][1],
                                            dv * acc3[nn][2], 0.f);
                }
            }
        }
    }
}

// stage-2 aggregation: block per fine bucket, tiny LDS accumulator (1 KB),
// ~1024 edges/block (never a hotspot; R12's agg3f shape).
__global__ void __launch_bounds__(256)
k_agg3f(const float4* __restrict__ hs3, const unsigned int* __restrict__ srt,
        const int* __restrict__ ftails, float4* __restrict__ y3agg) {
    __shared__ float acc[64 * 4];
    int fb = blockIdx.x;
    int t = threadIdx.x;
    acc[t] = 0.f;  // 256 threads cover 256 floats
    __syncthreads();
    int cnt = ftails[fb];
    const unsigned int* lst = srt + (size_t)fb * FB_CAP;
    for (int i = t; i < cnt; i += 256) {
        unsigned int r = lst[i];
        float4 h = hs3[r & 0xFFFFFu];
        int dl = r >> 20;
        atomicAdd(&acc[dl * 4 + 0], h.x);
        atomicAdd(&acc[dl * 4 + 1], h.y);
        atomicAdd(&acc[dl * 4 + 2], h.z);
    }
    __syncthreads();
    if (t < 64)
        y3agg[fb * 64 + t] = make_float4(acc[t * 4], acc[t * 4 + 1], acc[t * 4 + 2], 0.f);
}

// stage-2 BN stats over y_final = dinv*(y3agg + 2*hs3) + b2
__global__ void __launch_bounds__(256)
k_bnstats3(const float4* __restrict__ y3agg, const float4* __restrict__ hs3,
           const float* __restrict__ dinv, const float* __restrict__ b2,
           float* __restrict__ bnsum) {
    int v = blockIdx.x * blockDim.x + threadIdx.x;
    float y0 = 0.f, y1 = 0.f, y2 = 0.f;
    if (v < N_NODES) {
        float dv = dinv[v];
        float4 ya = y3agg[v];
        float4 h = hs3[v];
        y0 = dv * (ya.x + 2.f * h.x) + b2[0];
        y1 = dv * (ya.y + 2.f * h.y) + b2[1];
        y2 = dv * (ya.z + 2.f * h.z) + b2[2];
    }
    __shared__ float sm[256];
    float vals[6] = {y0, y1, y2, y0 * y0, y1 * y1, y2 * y2};
    for (int c = 0; c < 6; ++c) {
        sm[threadIdx.x] = (v < N_NODES) ? vals[c] : 0.f;
        __syncthreads();
        for (int off = 128; off > 0; off >>= 1) {
            if (threadIdx.x < off) sm[threadIdx.x] += sm[threadIdx.x + off];
            __syncthreads();
        }
        if (threadIdx.x == 0) atomicAdd(&bnsum[c], sm[0]);
        __syncthreads();
    }
}

// final stage post: BN + pool(3,1) + leaky + 3x3 linear + leaky
__global__ void k_post3(const float4* __restrict__ y3agg, const float4* __restrict__ hs3,
                        const float* __restrict__ dinv, const float* __restrict__ b2,
                        const float* __restrict__ bnsum,
                        const float* __restrict__ g, const float* __restrict__ bb,
                        const float* __restrict__ lw, const float* __restrict__ lb,
                        float* __restrict__ out) {
    int v = blockIdx.x * blockDim.x + threadIdx.x;
    if (v >= N_NODES) return;
    float inv_n = 1.0f / (float)N_NODES;
    float sc[3], sh[3];
#pragma unroll
    for (int c = 0; c < 3; ++c) {
        float mean = bnsum[c] * inv_n;
        float var = fmaxf(bnsum[3 + c] * inv_n - mean * mean, 0.f);
        sc[c] = g[c] * rsqrtf(var + 1e-5f);
        sh[c] = bb[c] - mean * sc[c];
    }
    float dv = dinv[v];
    float4 ya = y3agg[v];
    float4 h = hs3[v];
    float z0 = fmaf(dv * (ya.x + 2.f * h.x) + b2[0], sc[0], sh[0]);
    float z1 = fmaf(dv * (ya.y + 2.f * h.y) + b2[1], sc[1], sh[1]);
    float z2 = fmaf(dv * (ya.z + 2.f * h.z) + b2[2], sc[2], sh[2]);
    float p0 = fmaxf(z0, z1);
    float p1 = fmaxf(p0, z2);
    float p2 = fmaxf(z1, z2);
    float a0 = leaky(p0), a1 = leaky(p1), a2 = leaky(p2);
    float o0 = leaky(lb[0] + a0 * lw[0] + a1 * lw[1] + a2 * lw[2]);
    float o1 = leaky(lb[1] + a0 * lw[3] + a1 * lw[4] + a2 * lw[5]);
    float o2 = leaky(lb[2] + a0 * lw[6] + a1 * lw[7] + a2 * lw[8]);
    out[v * 3 + 0] = o0;
    out[v * 3 + 1] = o1;
    out[v * 3 + 2] = o2;
}

// ---------------- launcher ----------------

extern "C" void kernel_launch(void* const* d_in, const int* in_sizes, int n_in,
                              void* d_out, int out_size, void* d_ws, size_t ws_size,
                              hipStream_t stream) {
    const float* x  = (const float*)d_in[0];
    const int*   ei = (const int*)d_in[1];
    const float* w0 = (const float*)d_in[2];
    const float* b0 = (const float*)d_in[3];
    const float* g0 = (const float*)d_in[4];
    const float* bb0 = (const float*)d_in[5];
    const float* lw0 = (const float*)d_in[6];
    const float* lb0 = (const float*)d_in[7];
    const float* w1 = (const float*)d_in[8];
    const float* b1 = (const float*)d_in[9];
    const float* g1 = (const float*)d_in[10];
    const float* bb1 = (const float*)d_in[11];
    const float* lw1 = (const float*)d_in[12];
    const float* lb1 = (const float*)d_in[13];
    const float* w2 = (const float*)d_in[14];
    const float* b2 = (const float*)d_in[15];
    const float* g2 = (const float*)d_in[16];
    const float* bb2 = (const float*)d_in[17];
    const float* lw2 = (const float*)d_in[18];
    const float* lb2 = (const float*)d_in[19];
    float* out = (float*)d_out;

    // workspace layout (16B-aligned first)
    char* w = (char*)d_ws;
    float* yagg = (float*)w;       w += (size_t)N_NODES * 64 * 4;        // 20.48 MB
    unsigned int* srt = (unsigned int*)w; w += ((size_t)NFB * FB_CAP + 64) * 4;  // 6.4 MB (+pad)
    unsigned int* fpairs = (unsigned int*)w; w += (size_t)NFB * FB_CAP * 4;      // 6.4 MB
    bf16* hs = (bf16*)w;           w += (size_t)N_NODES * 64 * 2;        // 10.24 MB
    float4* hs3 = (float4*)w;      w += (size_t)N_NODES * 16;            // 1.28 MB
    float4* y3agg = (float4*)w;    w += (size_t)N_NODES * 16;            // 1.28 MB
    int* deg = (int*)w;            w += (size_t)N_NODES * 4;
    float* dinv = (float*)w;       w += (size_t)N_NODES * 4;
    float* bnsum = (float*)w;      w += 384 * 4;
    int* ctails = (int*)w;         w += NCB * 4;
    int* ftails = (int*)w;         w += NFB * 4;
    // cpairs overlays yagg (dead after k_refine; yagg memset comes later):
    // 64*21000*8 = 10.75 MB <= 20.48 MB
    int2* cpairs = (int2*)yagg;

    const int NB = (N_NODES + 255) / 256;  // 313

    // --- graph setup: two-level binning + per-bucket LDS sort (no scatter) ---
    k_zero<<<NB, 256, 0, stream>>>(deg, bnsum, ctails, ftails);
    k_part<<<N_EDGES / EPB, 256, 0, stream>>>(ei, cpairs, ctails);
    k_deg_bkt<<<2048, 256, 0, stream>>>(cpairs, ctails, deg);
    k_refine<<<64 * 16, 256, 0, stream>>>(cpairs, ctails, ftails, fpairs);
    k_sortfine<<<NFB, 256, 0, stream>>>(fpairs, ftails, srt);
    k_dinv<<<NB, 256, 0, stream>>>(deg, dinv);

    // --- stage 0 ---
    k_h0s<<<(N_NODES * 64 + 255) / 256, 256, 0, stream>>>(x, w0, dinv, hs);
    hipMemsetAsync(yagg, 0, (size_t)N_NODES * 64 * 4, stream);  // cpairs dead now
    k_agg_srt<<<(NFB * SPB + 3) / 4, 256, 0, stream>>>(hs, srt, ftails, yagg);
    k_bnstats<<<640, 256, 0, stream>>>(yagg, hs, dinv, b0, bnsum);
    k_post64<1, 0><<<1250, 128, 0, stream>>>(yagg, hs, dinv, b0, bnsum, g0, bb0,
                                             lw0, lb0, w1, hs, nullptr);

    // --- stage 1 ---
    hipMemsetAsync(yagg, 0, (size_t)N_NODES * 64 * 4, stream);
    k_agg_srt<<<(NFB * SPB + 3) / 4, 256, 0, stream>>>(hs, srt, ftails, yagg);
    k_bnstats<<<640, 256, 0, stream>>>(yagg, hs, dinv, b1, bnsum + 128);
    k_post64<2, 1><<<1250, 128, 0, stream>>>(yagg, hs, dinv, b1, bnsum + 128, g1, bb1,
                                             lw1, lb1, w2, nullptr, hs3);

    // --- stage 2 (C=3) ---
    k_agg3f<<<NFB, 256, 0, stream>>>(hs3, srt, ftails, y3agg);
    k_bnstats3<<<NB, 256, 0, stream>>>(y3agg, hs3, dinv, b2, bnsum + 256);
    k_post3<<<NB, 256, 0, stream>>>(y3agg, hs3, dinv, b2, bnsum + 256,
                                    g2, bb2, lw2, lb2, out);
}

// Round 15
// 475.121 us; speedup vs baseline: 1.2500x; 1.2500x over previous
//
#include <hip/hip_runtime.h>
#include <hip/hip_bf16.h>
#include <math.h>

#define N_NODES 80000
#define N_EDGES 1280000
#define CHUNK 128
#define N_CHUNKS (N_EDGES / CHUNK)  // 10000
#define NBKT 8
#define BKT_DIV 10000               // bucket = dst / 10000  -> 0..7
#define BKT_CAP 165000              // mean 160000, sigma ~374; huge margin
#define EPB 1280                    // edges per k_part block (grid 1000)

typedef __hip_bfloat16 bf16;

__device__ __forceinline__ float leaky(float x) { return x >= 0.f ? x : 0.01f * x; }

// ---------------- setup kernels ----------------

__global__ void k_zero(int* deg, float* bnsums, int* tails) {
    int i = blockIdx.x * blockDim.x + threadIdx.x;
    if (i < N_NODES) deg[i] = 0;
    if (i < 384) bnsums[i] = 0.f;
    if (i < NBKT) tails[i] = 0;
}

// pass 1: bin raw (src,dst) pairs by dst-range; block bulk-reserves regions.
__global__ void __launch_bounds__(256)
k_part(const int* __restrict__ ei, int2* __restrict__ pairs,
       int* __restrict__ tails) {
    __shared__ int cnt[NBKT], off[NBKT];
    int t = threadIdx.x;
    if (t < NBKT) cnt[t] = 0;
    __syncthreads();
    int base = blockIdx.x * EPB;
    int2 loc[5];
#pragma unroll
    for (int u = 0; u < 5; ++u) {
        int e = base + u * 256 + t;
        int s = ei[e], d = ei[N_EDGES + e];
        loc[u] = make_int2(s, d);
        atomicAdd(&cnt[d / BKT_DIV], 1);
    }
    __syncthreads();
    if (t < NBKT) off[t] = atomicAdd(&tails[t], cnt[t]);
    __syncthreads();
#pragma unroll
    for (int u = 0; u < 5; ++u) {
        int b = loc[u].y / BKT_DIV;
        int pos = atomicAdd(&off[b], 1);
        pairs[(size_t)b * BKT_CAP + pos] = loc[u];
    }
}

// deg counting, bucket-pinned (atomics confined to a 40 KB dst slice).
__global__ void __launch_bounds__(256)
k_deg_bkt(const int2* __restrict__ pairs, const int* __restrict__ tails,
          int* __restrict__ deg) {
    int bucket = blockIdx.x & 7;
    int jb = blockIdx.x >> 3;
    int nb = gridDim.x >> 3;
    int cnt = tails[bucket];
    const int2* lst = pairs + (size_t)bucket * BKT_CAP;
    for (int i = jb * 256 + threadIdx.x; i < cnt; i += nb * 256)
        atomicAdd(&deg[lst[i].y], 1);
}

__global__ void k_scanA(const int* __restrict__ deg, int* __restrict__ partial,
                        float* __restrict__ dinv) {
    __shared__ int s[256];
    int t = threadIdx.x;
    int i = blockIdx.x * 256 + t;
    int v = (i < N_NODES) ? deg[i] : 0;
    if (i < N_NODES) dinv[i] = rsqrtf((float)v + 2.0f);  // + self-loop weight 2
    s[t] = v;
    __syncthreads();
    for (int off = 128; off > 0; off >>= 1) {
        if (t < off) s[t] += s[t + off];
        __syncthreads();
    }
    if (t == 0) partial[blockIdx.x] = s[0];
}

__global__ void k_scanB(int* partial, int nb) {
    __shared__ int s[512];
    int t = threadIdx.x;
    int v = (t < nb) ? partial[t] : 0;
    s[t] = v;
    __syncthreads();
    for (int off = 1; off < 512; off <<= 1) {
        int x = (t >= off) ? s[t - off] : 0;
        __syncthreads();
        s[t] += x;
        __syncthreads();
    }
    if (t < nb) partial[t] = s[t] - v;  // exclusive
}

__global__ void k_scanC(const int* __restrict__ deg, const int* __restrict__ partial,
                        int* __restrict__ cursor) {
    __shared__ int s[256];
    int t = threadIdx.x;
    int i = blockIdx.x * 256 + t;
    int v = (i < N_NODES) ? deg[i] : 0;
    s[t] = v;
    __syncthreads();
    for (int off = 1; off < 256; off <<= 1) {
        int x = (t >= off) ? s[t - off] : 0;
        __syncthreads();
        s[t] += x;
        __syncthreads();
    }
    if (i < N_NODES) cursor[i] = partial[blockIdx.x] + s[t] - v;
}

// pass 2: per-bucket CSR scatter (plain stores; NT falsified in R13).
__global__ void __launch_bounds__(256)
k_scatter2(const int2* __restrict__ pairs, const int* __restrict__ tails,
           int* __restrict__ cursor, int2* __restrict__ ed2) {
    int bucket = blockIdx.x & 7;
    int jb = blockIdx.x >> 3;
    int nb = gridDim.x >> 3;
    int cnt = tails[bucket];
    const int2* lst = pairs + (size_t)bucket * BKT_CAP;
    for (int i = jb * 256 + threadIdx.x; i < cnt; i += nb * 256) {
        int2 pr = lst[i];
        int p = atomicAdd(&cursor[pr.y], 1);
        ed2[p] = pr;
    }
}

// h0 = x @ W0; hs = bf16(dinv*h0); also zero-inits yagg (replaces memset #1)
__global__ void k_h0s(const float* __restrict__ x, const float* __restrict__ W0,
                      const float* __restrict__ dinv, bf16* __restrict__ hs,
                      float* __restrict__ yagg) {
    int tid = blockIdx.x * blockDim.x + threadIdx.x;
    if (tid < N_NODES * 64) {
        int v = tid >> 6, c = tid & 63;
        float x0 = x[v * 3], x1 = x[v * 3 + 1], x2 = x[v * 3 + 2];
        float h = x0 * W0[c] + x1 * W0[64 + c] + x2 * W0[128 + c];
        hs[tid] = __float2bfloat16(dinv[v] * h);
        yagg[tid] = 0.f;
    }
}

// ---------------- per-stage kernels ----------------

// segmented edge-stream aggregation over CSR-sorted records (R10 structure).
// Interior segments -> plain store; leading/trailing -> atomicAdd (~2/chunk).
// yagg must be zero-initialized.
__global__ void __launch_bounds__(256)
k_agg_seg(const bf16* __restrict__ hs, const int2* __restrict__ ed2,
          float* __restrict__ yagg) {
    int lane = threadIdx.x & 63;
    int wid = (blockIdx.x * blockDim.x + threadIdx.x) >> 6;
    if (wid >= N_CHUNKS) return;
    int e = wid * CHUNK;
    int2 c[8];
#pragma unroll
    for (int u = 0; u < 8; ++u) c[u] = ed2[e + u];
    float acc = 0.f;
    int cur = __builtin_amdgcn_readfirstlane(c[0].y);
    bool lead = true;  // current segment may extend into the previous chunk
    for (int b = 0; b < CHUNK / 8; ++b) {
        float pv[8];
#pragma unroll
        for (int u = 0; u < 8; ++u)
            pv[u] = __bfloat162float(hs[(size_t)c[u].x * 64 + lane]);
        int2 cn[8];
        if (b < CHUNK / 8 - 1) {
            int en = e + 8;
#pragma unroll
            for (int u = 0; u < 8; ++u) cn[u] = ed2[en + u];
        }
#pragma unroll
        for (int u = 0; u < 8; ++u) {
            int du = __builtin_amdgcn_readfirstlane(c[u].y);
            if (du != cur) {
                if (lead) {
                    atomicAdd(&yagg[(size_t)cur * 64 + lane], acc);
                    lead = false;
                } else {
                    yagg[(size_t)cur * 64 + lane] = acc;  // exclusive owner
                }
                acc = 0.f;
                cur = du;
            }
            acc += pv[u];
        }
        e += 8;
        if (b < CHUNK / 8 - 1) {
#pragma unroll
            for (int u = 0; u < 8; ++u) c[u] = cn[u];
        }
    }
    atomicAdd(&yagg[(size_t)cur * 64 + lane], acc);  // trailing: may straddle
}

// per-channel sum/sumsq of y_final = dinv[v]*(yagg + 2*hs_self) + bias[c]
__global__ void __launch_bounds__(256)
k_bnstats(const float* __restrict__ yagg, const bf16* __restrict__ hs,
          const float* __restrict__ dinv, const float* __restrict__ bias,
          float* __restrict__ bnsum) {
    int tid = blockIdx.x * blockDim.x + threadIdx.x;
    int stride = gridDim.x * blockDim.x;  // multiple of 64 -> lane == channel
    float bc = bias[tid & 63];
    float bs = 0.f, bss = 0.f;
    for (size_t i = tid; i < (size_t)N_NODES * 64; i += stride) {
        float comb = yagg[i] + 2.f * __bfloat162float(hs[i]);
        float yf = dinv[i >> 6] * comb + bc;
        bs += yf;
        bss += yf * yf;
    }
    __shared__ float s1[256], s2[256];
    s1[threadIdx.x] = bs;
    s2[threadIdx.x] = bss;
    __syncthreads();
    if (threadIdx.x < 64) {
        float t1 = s1[threadIdx.x] + s1[threadIdx.x + 64] + s1[threadIdx.x + 128] + s1[threadIdx.x + 192];
        float t2 = s2[threadIdx.x] + s2[threadIdx.x + 64] + s2[threadIdx.x + 128] + s2[threadIdx.x + 192];
        atomicAdd(&bnsum[threadIdx.x], t1);
        atomicAdd(&bnsum[64 + threadIdx.x], t2);
    }
}

// BN + maxpool + leaky + (a@lw.T+lb) + leaky + second matmul, register-tiled.
// Phase 1 input: y_final = dinv*(yagg + 2*hs_self) + bias (bias folded into BN shift).
// ZY: zero yagg element right after reading it (replaces stage-1 memset).
// MODE 0: phase3 = o @ Wn (64x64) -> hs_next = bf16(dinv*hn).
// MODE 1: phase3 = o @ Wn (64x3)  -> hs3 = float4(dinv*h3).
template <int P, int MODE, bool ZY>
__global__ void __launch_bounds__(128)
k_post64(float* __restrict__ yagg, const bf16* __restrict__ hs,
         const float* __restrict__ dinv, const float* __restrict__ bias,
         const float* __restrict__ bnsum,
         const float* __restrict__ g, const float* __restrict__ bb,
         const float* __restrict__ lw, const float* __restrict__ lb,
         const float* __restrict__ Wn, bf16* __restrict__ hsout,
         float4* __restrict__ hs3) {
    __shared__ float s_aT[2][64 * 36];  // per-wave activation tile (transposed), reused as oT
    __shared__ float s_lwT[64 * 64];    // lw transposed: [k][c]
    __shared__ float s_Wn[MODE == 0 ? 64 * 64 : 64 * 3];
    int t = threadIdx.x;
    int w = t >> 6, lane = t & 63;
    for (int k0 = t; k0 < 4096; k0 += 128) {
        int kk = k0 >> 6, cc = k0 & 63;
        s_lwT[kk * 64 + cc] = lw[cc * 64 + kk];
        if (MODE == 0) s_Wn[k0] = Wn[k0];
    }
    if (MODE == 1) {
        for (int i = t; i < 64 * 3; i += 128) s_Wn[i] = Wn[i];
    }
    float inv_n = 1.0f / (float)N_NODES;
    float mean = bnsum[lane] * inv_n;
    float var = fmaxf(bnsum[64 + lane] * inv_n - mean * mean, 0.f);
    float sc = g[lane] * rsqrtf(var + 1e-5f);
    float sh = bb[lane] - mean * sc;
    float shb = fmaf(sc, bias[lane], sh);  // folds GCN bias into BN shift
    int c0 = (lane >> 3) * 8, n0 = (lane & 7) * 4;
    float lbv[8];
#pragma unroll
    for (int i = 0; i < 8; ++i) lbv[i] = lb[c0 + i];
    float* aT = s_aT[w];

    for (int tile = blockIdx.x; tile < N_NODES / 64; tile += gridDim.x) {
        int nbase = tile * 64 + w * 32;
        __syncthreads();  // also covers initial weight-fill -> first use
#pragma unroll 4
        for (int i = 0; i < 32; ++i) {
            size_t idx = (size_t)(nbase + i) * 64 + lane;
            float comb = yagg[idx] + 2.f * __bfloat162float(hs[idx]);
            if (ZY) yagg[idx] = 0.f;  // element is dead after this read
            float z = fmaf(sc * dinv[nbase + i], comb, shb);
            float m = z;
#pragma unroll
            for (int d = 1; d <= P; ++d) {
                float up = __shfl(z, lane + d);
                float dn = __shfl(z, lane - d);
                m = fmaxf(m, (lane + d < 64) ? up : -INFINITY);
                m = fmaxf(m, (lane - d >= 0) ? dn : -INFINITY);
            }
            aT[lane * 36 + i] = leaky(m);
        }
        __syncthreads();
        // phase 2: o = leaky(a @ lw.T + lb)
        float acc[4][8];
#pragma unroll
        for (int nn = 0; nn < 4; ++nn)
#pragma unroll
            for (int i = 0; i < 8; ++i) acc[nn][i] = lbv[i];
#pragma unroll 8
        for (int k = 0; k < 64; ++k) {
            float4 av = *(const float4*)&aT[k * 36 + n0];
            float4 w0 = *(const float4*)&s_lwT[k * 64 + c0];
            float4 w1 = *(const float4*)&s_lwT[k * 64 + c0 + 4];
            float a4[4] = {av.x, av.y, av.z, av.w};
            float wv[8] = {w0.x, w0.y, w0.z, w0.w, w1.x, w1.y, w1.z, w1.w};
#pragma unroll
            for (int nn = 0; nn < 4; ++nn)
#pragma unroll
                for (int i = 0; i < 8; ++i) acc[nn][i] = fmaf(a4[nn], wv[i], acc[nn][i]);
        }
#pragma unroll
        for (int nn = 0; nn < 4; ++nn)
#pragma unroll
            for (int i = 0; i < 8; ++i) acc[nn][i] = leaky(acc[nn][i]);

        // write oT (aliases aT; same-wave LDS program order is safe)
#pragma unroll
        for (int i = 0; i < 8; ++i) {
            float4 ov = make_float4(acc[0][i], acc[1][i], acc[2][i], acc[3][i]);
            *(float4*)&aT[(c0 + i) * 36 + n0] = ov;
        }
        if (MODE == 0) {
            float acc2[4][8];
#pragma unroll
            for (int nn = 0; nn < 4; ++nn)
#pragma unroll
                for (int i = 0; i < 8; ++i) acc2[nn][i] = 0.f;
#pragma unroll 8
            for (int k = 0; k < 64; ++k) {
                float4 av = *(const float4*)&aT[k * 36 + n0];
                float4 w0 = *(const float4*)&s_Wn[k * 64 + c0];
                float4 w1 = *(const float4*)&s_Wn[k * 64 + c0 + 4];
                float a4[4] = {av.x, av.y, av.z, av.w};
                float wv[8] = {w0.x, w0.y, w0.z, w0.w, w1.x, w1.y, w1.z, w1.w};
#pragma unroll
                for (int nn = 0; nn < 4; ++nn)
#pragma unroll
                    for (int i = 0; i < 8; ++i) acc2[nn][i] = fmaf(a4[nn], wv[i], acc2[nn][i]);
            }
#pragma unroll
            for (int nn = 0; nn < 4; ++nn) {
                int node = nbase + n0 + nn;
                float dv = dinv[node];
                bf16 pk[8];
#pragma unroll
                for (int i = 0; i < 8; ++i) pk[i] = __float2bfloat16(dv * acc2[nn][i]);
                *(uint4*)&hsout[(size_t)node * 64 + c0] = *(uint4*)pk;
            }
        } else {
            // proj fused: h3 = o @ w2 (64x3); 8 lanes duplicate, c0==0 writes
            float acc3[4][3];
#pragma unroll
            for (int nn = 0; nn < 4; ++nn)
#pragma unroll
                for (int j = 0; j < 3; ++j) acc3[nn][j] = 0.f;
#pragma unroll 8
            for (int k = 0; k < 64; ++k) {
                float4 av = *(const float4*)&aT[k * 36 + n0];
                float a4[4] = {av.x, av.y, av.z, av.w};
                float w0 = s_Wn[k * 3 + 0], w1 = s_Wn[k * 3 + 1], w2v = s_Wn[k * 3 + 2];
#pragma unroll
                for (int nn = 0; nn < 4; ++nn) {
                    acc3[nn][0] = fmaf(a4[nn], w0, acc3[nn][0]);
                    acc3[nn][1] = fmaf(a4[nn], w1, acc3[nn][1]);
                    acc3[nn][2] = fmaf(a4[nn], w2v, acc3[nn][2]);
                }
            }
            if (c0 == 0) {
#pragma unroll
                for (int nn = 0; nn < 4; ++nn) {
                    int node = nbase + n0 + nn;
                    float dv = dinv[node];
                    hs3[node] = make_float4(dv * acc3[nn][0], dv * acc3[nn][1],
                                            dv * acc3[nn][2], 0.f);
                }
            }
        }
    }
}

// stage-2: aggregation (thread-per-node over CSR) + final y3 + BN stats, fused.
// Writes y3 final = dinv*(agg + 2*hs3) + b2 and accumulates bnsum.
__global__ void __launch_bounds__(256)
k_agg3(const float4* __restrict__ hs3, const int* __restrict__ cursor,
       const int2* __restrict__ ed2, const float* __restrict__ dinv,
       const float* __restrict__ b2, float4* __restrict__ y3,
       float* __restrict__ bnsum) {
    int v = blockIdx.x * blockDim.x + threadIdx.x;
    float y0 = 0.f, y1 = 0.f, y2 = 0.f;
    bool valid = v < N_NODES;
    if (valid) {
        int end = cursor[v];
        int start = (v == 0) ? 0 : cursor[v - 1];
        float a0 = 0.f, a1 = 0.f, a2 = 0.f;
        int e = start;
        for (; e + 4 <= end; e += 4) {
            int2 c[4];
#pragma unroll
            for (int u = 0; u < 4; ++u) c[u] = ed2[e + u];
#pragma unroll
            for (int u = 0; u < 4; ++u) {
                float4 h = hs3[c[u].x];
                a0 += h.x; a1 += h.y; a2 += h.z;
            }
        }
        for (; e < end; ++e) {
            float4 h = hs3[ed2[e].x];
            a0 += h.x; a1 += h.y; a2 += h.z;
        }
        float dv = dinv[v];
        float4 hsv = hs3[v];
        y0 = dv * (a0 + 2.f * hsv.x) + b2[0];
        y1 = dv * (a1 + 2.f * hsv.y) + b2[1];
        y2 = dv * (a2 + 2.f * hsv.z) + b2[2];
        y3[v] = make_float4(y0, y1, y2, 0.f);
    }
    __shared__ float sm[256];
    float vals[6] = {y0, y1, y2, y0 * y0, y1 * y1, y2 * y2};
    for (int c = 0; c < 6; ++c) {
        sm[threadIdx.x] = valid ? vals[c] : 0.f;
        __syncthreads();
        for (int off = 128; off > 0; off >>= 1) {
            if (threadIdx.x < off) sm[threadIdx.x] += sm[threadIdx.x + off];
            __syncthreads();
        }
        if (threadIdx.x == 0) atomicAdd(&bnsum[c], sm[0]);
        __syncthreads();
    }
}

// final stage post: BN + pool(3,1) + leaky + 3x3 linear + leaky (y3 is final input)
__global__ void k_post3(const float4* __restrict__ y3, const float* __restrict__ bnsum,
                        const float* __restrict__ g, const float* __restrict__ bb,
                        const float* __restrict__ lw, const float* __restrict__ lb,
                        float* __restrict__ out) {
    int v = blockIdx.x * blockDim.x + threadIdx.x;
    if (v >= N_NODES) return;
    float inv_n = 1.0f / (float)N_NODES;
    float sc[3], sh[3];
#pragma unroll
    for (int c = 0; c < 3; ++c) {
        float mean = bnsum[c] * inv_n;
        float var = fmaxf(bnsum[3 + c] * inv_n - mean * mean, 0.f);
        sc[c] = g[c] * rsqrtf(var + 1e-5f);
        sh[c] = bb[c] - mean * sc[c];
    }
    float4 y = y3[v];
    float z0 = fmaf(y.x, sc[0], sh[0]);
    float z1 = fmaf(y.y, sc[1], sh[1]);
    float z2 = fmaf(y.z, sc[2], sh[2]);
    float p0 = fmaxf(z0, z1);
    float p1 = fmaxf(p0, z2);
    float p2 = fmaxf(z1, z2);
    float a0 = leaky(p0), a1 = leaky(p1), a2 = leaky(p2);
    float o0 = leaky(lb[0] + a0 * lw[0] + a1 * lw[1] + a2 * lw[2]);
    float o1 = leaky(lb[1] + a0 * lw[3] + a1 * lw[4] + a2 * lw[5]);
    float o2 = leaky(lb[2] + a0 * lw[6] + a1 * lw[7] + a2 * lw[8]);
    out[v * 3 + 0] = o0;
    out[v * 3 + 1] = o1;
    out[v * 3 + 2] = o2;
}

// ---------------- launcher ----------------

extern "C" void kernel_launch(void* const* d_in, const int* in_sizes, int n_in,
                              void* d_out, int out_size, void* d_ws, size_t ws_size,
                              hipStream_t stream) {
    const float* x  = (const float*)d_in[0];
    const int*   ei = (const int*)d_in[1];
    const float* w0 = (const float*)d_in[2];
    const float* b0 = (const float*)d_in[3];
    const float* g0 = (const float*)d_in[4];
    const float* bb0 = (const float*)d_in[5];
    const float* lw0 = (const float*)d_in[6];
    const float* lb0 = (const float*)d_in[7];
    const float* w1 = (const float*)d_in[8];
    const float* b1 = (const float*)d_in[9];
    const float* g1 = (const float*)d_in[10];
    const float* bb1 = (const float*)d_in[11];
    const float* lw1 = (const float*)d_in[12];
    const float* lb1 = (const float*)d_in[13];
    const float* w2 = (const float*)d_in[14];
    const float* b2 = (const float*)d_in[15];
    const float* g2 = (const float*)d_in[16];
    const float* bb2 = (const float*)d_in[17];
    const float* lw2 = (const float*)d_in[18];
    const float* lb2 = (const float*)d_in[19];
    float* out = (float*)d_out;

    // workspace layout (16B-aligned first)
    char* w = (char*)d_ws;
    float* yagg = (float*)w;       w += (size_t)N_NODES * 64 * 4;   // 20.48 MB
    int2* ed2 = (int2*)w;          w += (size_t)N_EDGES * 8;        // 10.24 MB
    bf16* hs = (bf16*)w;           w += (size_t)N_NODES * 64 * 2;   // 10.24 MB
    float4* hs3 = (float4*)w;      w += (size_t)N_NODES * 16;       // 1.28 MB
    float4* y3 = (float4*)w;       w += (size_t)N_NODES * 16;       // 1.28 MB
    int* deg = (int*)w;            w += (size_t)N_NODES * 4;
    float* dinv = (float*)w;       w += (size_t)N_NODES * 4;
    int* cursor = (int*)w;         w += (size_t)N_NODES * 4;
    int* partial = (int*)w;        w += 512 * 4;
    float* bnsum = (float*)w;      w += 384 * 4;
    int* tails = (int*)w;          w += 16 * 4;
    // pairs overlays yagg (dead by the time k_h0s zero-inits yagg)
    int2* pairs = (int2*)yagg;

    const int NB = (N_NODES + 255) / 256;  // 313

    // --- graph/CSR setup ---
    k_zero<<<NB, 256, 0, stream>>>(deg, bnsum, tails);
    k_part<<<N_EDGES / EPB, 256, 0, stream>>>(ei, pairs, tails);
    k_deg_bkt<<<2048, 256, 0, stream>>>(pairs, tails, deg);
    k_scanA<<<NB, 256, 0, stream>>>(deg, partial, dinv);
    k_scanB<<<1, 512, 0, stream>>>(partial, NB);
    k_scanC<<<NB, 256, 0, stream>>>(deg, partial, cursor);
    k_scatter2<<<2048, 256, 0, stream>>>(pairs, tails, cursor, ed2);

    // --- stage 0 ---
    k_h0s<<<(N_NODES * 64 + 255) / 256, 256, 0, stream>>>(x, w0, dinv, hs, yagg);
    k_agg_seg<<<2500, 256, 0, stream>>>(hs, ed2, yagg);
    k_bnstats<<<640, 256, 0, stream>>>(yagg, hs, dinv, b0, bnsum);
    // ZY=true: re-zeroes yagg for stage 1 while reading it
    k_post64<1, 0, true><<<1250, 128, 0, stream>>>(yagg, hs, dinv, b0, bnsum, g0, bb0,
                                                   lw0, lb0, w1, hs, nullptr);

    // --- stage 1 ---
    k_agg_seg<<<2500, 256, 0, stream>>>(hs, ed2, yagg);
    k_bnstats<<<640, 256, 0, stream>>>(yagg, hs, dinv, b1, bnsum + 128);
    k_post64<2, 1, false><<<1250, 128, 0, stream>>>(yagg, hs, dinv, b1, bnsum + 128, g1, bb1,
                                                    lw1, lb1, w2, nullptr, hs3);

    // --- stage 2 (C=3): agg + BN stats fused ---
    k_agg3<<<NB, 256, 0, stream>>>(hs3, cursor, ed2, dinv, b2, y3, bnsum + 256);
    k_post3<<<NB, 256, 0, stream>>>(y3, bnsum + 256, g2, bb2, lw2, lb2, out);
}

// Round 16
// 435.948 us; speedup vs baseline: 1.3623x; 1.0899x over previous
//
#include <hip/hip_runtime.h>
#include <hip/hip_bf16.h>
#include <math.h>

#define N_NODES 80000
#define N_EDGES 1280000
#define CHUNK 128
#define N_CHUNKS (N_EDGES / CHUNK)  // 10000
#define NCB 64
#define CB_DIV 1250                 // coarse bucket = dst / 1250 -> 0..63
#define CB_CAP 21000                // mean 20000, +7 sigma
#define NFB 1250                    // fine bucket = dst >> 6 (64 nodes each)
#define FB_CAP 1280                 // mean 1024, +8 sigma
#define EPB 1280                    // edges per k_part block (grid 1000)

typedef __hip_bfloat16 bf16;

__device__ __forceinline__ float leaky(float x) { return x >= 0.f ? x : 0.01f * x; }

// ---------------- setup kernels ----------------

__global__ void k_zero(int* deg, float* bnsums, int* ctails, int* ftails) {
    int i = blockIdx.x * blockDim.x + threadIdx.x;
    if (i < N_NODES) deg[i] = 0;
    if (i < 384) bnsums[i] = 0.f;
    if (i < NCB) ctails[i] = 0;
    if (i < NFB) ftails[i] = 0;
}

// pass 1: 64-way coarse bin of (src,dst) pairs; block bulk-reserves regions,
// threads write ~20-edge runs. No random global scatter.
__global__ void __launch_bounds__(256)
k_part(const int* __restrict__ ei, int2* __restrict__ cpairs,
       int* __restrict__ ctails) {
    __shared__ int cnt[NCB], off[NCB];
    int t = threadIdx.x;
    if (t < NCB) cnt[t] = 0;
    __syncthreads();
    int base = blockIdx.x * EPB;
    int2 loc[5];
#pragma unroll
    for (int u = 0; u < 5; ++u) {
        int e = base + u * 256 + t;
        int s = ei[e], d = ei[N_EDGES + e];
        loc[u] = make_int2(s, d);
        atomicAdd(&cnt[d / CB_DIV], 1);
    }
    __syncthreads();
    if (t < NCB) off[t] = atomicAdd(&ctails[t], cnt[t]);
    __syncthreads();
#pragma unroll
    for (int u = 0; u < 5; ++u) {
        int b = loc[u].y / CB_DIV;
        int pos = atomicAdd(&off[b], 1);
        cpairs[(size_t)b * CB_CAP + pos] = loc[u];
    }
}

// deg counting, bucket-pinned (atomics confined to a 5 KB dst slice per bucket).
__global__ void __launch_bounds__(256)
k_deg_bkt(const int2* __restrict__ cpairs, const int* __restrict__ ctails,
          int* __restrict__ deg) {
    int bucket = blockIdx.x & 63;
    int jb = blockIdx.x >> 6;
    int nb = gridDim.x >> 6;
    int cnt = ctails[bucket];
    const int2* lst = cpairs + (size_t)bucket * CB_CAP;
    for (int i = jb * 256 + threadIdx.x; i < cnt; i += nb * 256)
        atomicAdd(&deg[lst[i].y], 1);
}

__global__ void k_scanA(const int* __restrict__ deg, int* __restrict__ partial,
                        float* __restrict__ dinv) {
    __shared__ int s[256];
    int t = threadIdx.x;
    int i = blockIdx.x * 256 + t;
    int v = (i < N_NODES) ? deg[i] : 0;
    if (i < N_NODES) dinv[i] = rsqrtf((float)v + 2.0f);  // + self-loop weight 2
    s[t] = v;
    __syncthreads();
    for (int off = 128; off > 0; off >>= 1) {
        if (t < off) s[t] += s[t + off];
        __syncthreads();
    }
    if (t == 0) partial[blockIdx.x] = s[0];
}

__global__ void k_scanB(int* partial, int nb) {
    __shared__ int s[512];
    int t = threadIdx.x;
    int v = (t < nb) ? partial[t] : 0;
    s[t] = v;
    __syncthreads();
    for (int off = 1; off < 512; off <<= 1) {
        int x = (t >= off) ? s[t - off] : 0;
        __syncthreads();
        s[t] += x;
        __syncthreads();
    }
    if (t < nb) partial[t] = s[t] - v;  // exclusive
}

// cursor[i] = row_start(i)  (exclusive prefix; NOT mutated afterwards)
__global__ void k_scanC(const int* __restrict__ deg, const int* __restrict__ partial,
                        int* __restrict__ cursor) {
    __shared__ int s[256];
    int t = threadIdx.x;
    int i = blockIdx.x * 256 + t;
    int v = (i < N_NODES) ? deg[i] : 0;
    s[t] = v;
    __syncthreads();
    for (int off = 1; off < 256; off <<= 1) {
        int x = (t >= off) ? s[t - off] : 0;
        __syncthreads();
        s[t] += x;
        __syncthreads();
    }
    if (i < N_NODES) cursor[i] = partial[blockIdx.x] + s[t] - v;
}

// pass 2: refine coarse bucket -> fine buckets of 64 nodes. LDS-staged strip,
// <=21 fine bins per coarse bucket, ~100-edge runs. Record: src | (dst&63)<<20.
__global__ void __launch_bounds__(256)
k_refine(const int2* __restrict__ cpairs, const int* __restrict__ ctails,
         int* __restrict__ ftails, unsigned int* __restrict__ fpairs) {
    __shared__ int2 s_ed[2048];  // 16 KB strip stage
    __shared__ int cnt2[32], off2[32];
    int b = blockIdx.x & 63;
    int j = blockIdx.x >> 6;
    int t = threadIdx.x;
    int cnt = ctails[b];
    int s0 = j * 2048;
    if (s0 >= cnt) return;
    int n = min(2048, cnt - s0);
    int fb0 = (b * CB_DIV) >> 6;
    int nbins = (((b + 1) * CB_DIV - 1) >> 6) - fb0 + 1;  // <= 21
    const int2* lst = cpairs + (size_t)b * CB_CAP + s0;
    for (int i = t; i < n; i += 256) s_ed[i] = lst[i];
    if (t < 32) cnt2[t] = 0;
    __syncthreads();
    for (int i = t; i < n; i += 256)
        atomicAdd(&cnt2[(s_ed[i].y >> 6) - fb0], 1);
    __syncthreads();
    if (t < nbins && cnt2[t] > 0) off2[t] = atomicAdd(&ftails[fb0 + t], cnt2[t]);
    __syncthreads();
    for (int i = t; i < n; i += 256) {
        int2 pr = s_ed[i];
        int fbl = (pr.y >> 6) - fb0;
        int pos = atomicAdd(&off2[fbl], 1);
        fpairs[(size_t)(fb0 + fbl) * FB_CAP + pos] =
            (unsigned int)pr.x | ((unsigned int)(pr.y & 63) << 20);
    }
}

// pass 3: per-fine-bucket LDS counting sort, then SEQUENTIAL write of sorted
// (src,dst) int2 records into the global CSR slot [cursor[fb*64], +cnt).
// Fully coalesced ~8 KB stream per block — replaces the random scatter.
__global__ void __launch_bounds__(256)
k_sortfine(const unsigned int* __restrict__ fpairs, const int* __restrict__ ftails,
           const int* __restrict__ cursor, int2* __restrict__ ed2) {
    __shared__ unsigned int stage[FB_CAP];
    __shared__ int hist[64], cur[64];
    int fb = blockIdx.x;
    int t = threadIdx.x;
    int cnt = ftails[fb];
    const unsigned int* lst = fpairs + (size_t)fb * FB_CAP;
    if (t < 64) hist[t] = 0;
    __syncthreads();
    for (int i = t; i < cnt; i += 256)
        atomicAdd(&hist[lst[i] >> 20], 1);
    __syncthreads();
    if (t == 0) {
        int s = 0;
        for (int j = 0; j < 64; ++j) { cur[j] = s; s += hist[j]; }
    }
    __syncthreads();
    for (int i = t; i < cnt; i += 256) {
        unsigned int r = lst[i];
        int p = atomicAdd(&cur[r >> 20], 1);
        stage[p] = r;
    }
    __syncthreads();
    int base = cursor[fb * 64];
    int node0 = fb * 64;
    for (int i = t; i < cnt; i += 256) {
        unsigned int r = stage[i];
        ed2[base + i] = make_int2((int)(r & 0xFFFFFu), node0 + (int)(r >> 20));
    }
}

// h0 = x @ W0; hs = bf16(dinv*h0); also zero-inits yagg (replaces memset #1)
__global__ void k_h0s(const float* __restrict__ x, const float* __restrict__ W0,
                      const float* __restrict__ dinv, bf16* __restrict__ hs,
                      float* __restrict__ yagg) {
    int tid = blockIdx.x * blockDim.x + threadIdx.x;
    if (tid < N_NODES * 64) {
        int v = tid >> 6, c = tid & 63;
        float x0 = x[v * 3], x1 = x[v * 3 + 1], x2 = x[v * 3 + 2];
        float h = x0 * W0[c] + x1 * W0[64 + c] + x2 * W0[128 + c];
        hs[tid] = __float2bfloat16(dinv[v] * h);
        yagg[tid] = 0.f;
    }
}

// ---------------- per-stage kernels ----------------

// segmented edge-stream aggregation over CSR-sorted records (R10 structure).
// Interior segments -> plain store; leading/trailing -> atomicAdd (~2/chunk).
// yagg must be zero-initialized.
__global__ void __launch_bounds__(256)
k_agg_seg(const bf16* __restrict__ hs, const int2* __restrict__ ed2,
          float* __restrict__ yagg) {
    int lane = threadIdx.x & 63;
    int wid = (blockIdx.x * blockDim.x + threadIdx.x) >> 6;
    if (wid >= N_CHUNKS) return;
    int e = wid * CHUNK;
    int2 c[8];
#pragma unroll
    for (int u = 0; u < 8; ++u) c[u] = ed2[e + u];
    float acc = 0.f;
    int cur = __builtin_amdgcn_readfirstlane(c[0].y);
    bool lead = true;  // current segment may extend into the previous chunk
    for (int b = 0; b < CHUNK / 8; ++b) {
        float pv[8];
#pragma unroll
        for (int u = 0; u < 8; ++u)
            pv[u] = __bfloat162float(hs[(size_t)c[u].x * 64 + lane]);
        int2 cn[8];
        if (b < CHUNK / 8 - 1) {
            int en = e + 8;
#pragma unroll
            for (int u = 0; u < 8; ++u) cn[u] = ed2[en + u];
        }
#pragma unroll
        for (int u = 0; u < 8; ++u) {
            int du = __builtin_amdgcn_readfirstlane(c[u].y);
            if (du != cur) {
                if (lead) {
                    atomicAdd(&yagg[(size_t)cur * 64 + lane], acc);
                    lead = false;
                } else {
                    yagg[(size_t)cur * 64 + lane] = acc;  // exclusive owner
                }
                acc = 0.f;
                cur = du;
            }
            acc += pv[u];
        }
        e += 8;
        if (b < CHUNK / 8 - 1) {
#pragma unroll
            for (int u = 0; u < 8; ++u) c[u] = cn[u];
        }
    }
    atomicAdd(&yagg[(size_t)cur * 64 + lane], acc);  // trailing: may straddle
}

// per-channel sum/sumsq of y_final = dinv[v]*(yagg + 2*hs_self) + bias[c]
__global__ void __launch_bounds__(256)
k_bnstats(const float* __restrict__ yagg, const bf16* __restrict__ hs,
          const float* __restrict__ dinv, const float* __restrict__ bias,
          float* __restrict__ bnsum) {
    int tid = blockIdx.x * blockDim.x + threadIdx.x;
    int stride = gridDim.x * blockDim.x;  // multiple of 64 -> lane == channel
    float bc = bias[tid & 63];
    float bs = 0.f, bss = 0.f;
    for (size_t i = tid; i < (size_t)N_NODES * 64; i += stride) {
        float comb = yagg[i] + 2.f * __bfloat162float(hs[i]);
        float yf = dinv[i >> 6] * comb + bc;
        bs += yf;
        bss += yf * yf;
    }
    __shared__ float s1[256], s2[256];
    s1[threadIdx.x] = bs;
    s2[threadIdx.x] = bss;
    __syncthreads();
    if (threadIdx.x < 64) {
        float t1 = s1[threadIdx.x] + s1[threadIdx.x + 64] + s1[threadIdx.x + 128] + s1[threadIdx.x + 192];
        float t2 = s2[threadIdx.x] + s2[threadIdx.x + 64] + s2[threadIdx.x + 128] + s2[threadIdx.x + 192];
        atomicAdd(&bnsum[threadIdx.x], t1);
        atomicAdd(&bnsum[64 + threadIdx.x], t2);
    }
}

// BN + maxpool + leaky + (a@lw.T+lb) + leaky + second matmul, register-tiled.
// Phase 1 input: y_final = dinv*(yagg + 2*hs_self) + bias (bias folded into BN shift).
// ZY: zero yagg element right after reading it (replaces stage-1 memset).
// MODE 0: phase3 = o @ Wn (64x64) -> hs_next = bf16(dinv*hn).
// MODE 1: phase3 = o @ Wn (64x3)  -> hs3 = float4(dinv*h3).
template <int P, int MODE, bool ZY>
__global__ void __launch_bounds__(128)
k_post64(float* __restrict__ yagg, const bf16* __restrict__ hs,
         const float* __restrict__ dinv, const float* __restrict__ bias,
         const float* __restrict__ bnsum,
         const float* __restrict__ g, const float* __restrict__ bb,
         const float* __restrict__ lw, const float* __restrict__ lb,
         const float* __restrict__ Wn, bf16* __restrict__ hsout,
         float4* __restrict__ hs3) {
    __shared__ float s_aT[2][64 * 36];  // per-wave activation tile (transposed), reused as oT
    __shared__ float s_lwT[64 * 64];    // lw transposed: [k][c]
    __shared__ float s_Wn[MODE == 0 ? 64 * 64 : 64 * 3];
    int t = threadIdx.x;
    int w = t >> 6, lane = t & 63;
    for (int k0 = t; k0 < 4096; k0 += 128) {
        int kk = k0 >> 6, cc = k0 & 63;
        s_lwT[kk * 64 + cc] = lw[cc * 64 + kk];
        if (MODE == 0) s_Wn[k0] = Wn[k0];
    }
    if (MODE == 1) {
        for (int i = t; i < 64 * 3; i += 128) s_Wn[i] = Wn[i];
    }
    float inv_n = 1.0f / (float)N_NODES;
    float mean = bnsum[lane] * inv_n;
    float var = fmaxf(bnsum[64 + lane] * inv_n - mean * mean, 0.f);
    float sc = g[lane] * rsqrtf(var + 1e-5f);
    float sh = bb[lane] - mean * sc;
    float shb = fmaf(sc, bias[lane], sh);  // folds GCN bias into BN shift
    int c0 = (lane >> 3) * 8, n0 = (lane & 7) * 4;
    float lbv[8];
#pragma unroll
    for (int i = 0; i < 8; ++i) lbv[i] = lb[c0 + i];
    float* aT = s_aT[w];

    for (int tile = blockIdx.x; tile < N_NODES / 64; tile += gridDim.x) {
        int nbase = tile * 64 + w * 32;
        __syncthreads();  // also covers initial weight-fill -> first use
#pragma unroll 4
        for (int i = 0; i < 32; ++i) {
            size_t idx = (size_t)(nbase + i) * 64 + lane;
            float comb = yagg[idx] + 2.f * __bfloat162float(hs[idx]);
            if (ZY) yagg[idx] = 0.f;  // element is dead after this read
            float z = fmaf(sc * dinv[nbase + i], comb, shb);
            float m = z;
#pragma unroll
            for (int d = 1; d <= P; ++d) {
                float up = __shfl(z, lane + d);
                float dn = __shfl(z, lane - d);
                m = fmaxf(m, (lane + d < 64) ? up : -INFINITY);
                m = fmaxf(m, (lane - d >= 0) ? dn : -INFINITY);
            }
            aT[lane * 36 + i] = leaky(m);
        }
        __syncthreads();
        // phase 2: o = leaky(a @ lw.T + lb)
        float acc[4][8];
#pragma unroll
        for (int nn = 0; nn < 4; ++nn)
#pragma unroll
            for (int i = 0; i < 8; ++i) acc[nn][i] = lbv[i];
#pragma unroll 8
        for (int k = 0; k < 64; ++k) {
            float4 av = *(const float4*)&aT[k * 36 + n0];
            float4 w0 = *(const float4*)&s_lwT[k * 64 + c0];
            float4 w1 = *(const float4*)&s_lwT[k * 64 + c0 + 4];
            float a4[4] = {av.x, av.y, av.z, av.w};
            float wv[8] = {w0.x, w0.y, w0.z, w0.w, w1.x, w1.y, w1.z, w1.w};
#pragma unroll
            for (int nn = 0; nn < 4; ++nn)
#pragma unroll
                for (int i = 0; i < 8; ++i) acc[nn][i] = fmaf(a4[nn], wv[i], acc[nn][i]);
        }
#pragma unroll
        for (int nn = 0; nn < 4; ++nn)
#pragma unroll
            for (int i = 0; i < 8; ++i) acc[nn][i] = leaky(acc[nn][i]);

        // write oT (aliases aT; same-wave LDS program order is safe)
#pragma unroll
        for (int i = 0; i < 8; ++i) {
            float4 ov = make_float4(acc[0][i], acc[1][i], acc[2][i], acc[3][i]);
            *(float4*)&aT[(c0 + i) * 36 + n0] = ov;
        }
        if (MODE == 0) {
            float acc2[4][8];
#pragma unroll
            for (int nn = 0; nn < 4; ++nn)
#pragma unroll
                for (int i = 0; i < 8; ++i) acc2[nn][i] = 0.f;
#pragma unroll 8
            for (int k = 0; k < 64; ++k) {
                float4 av = *(const float4*)&aT[k * 36 + n0];
                float4 w0 = *(const float4*)&s_Wn[k * 64 + c0];
                float4 w1 = *(const float4*)&s_Wn[k * 64 + c0 + 4];
                float a4[4] = {av.x, av.y, av.z, av.w};
                float wv[8] = {w0.x, w0.y, w0.z, w0.w, w1.x, w1.y, w1.z, w1.w};
#pragma unroll
                for (int nn = 0; nn < 4; ++nn)
#pragma unroll
                    for (int i = 0; i < 8; ++i) acc2[nn][i] = fmaf(a4[nn], wv[i], acc2[nn][i]);
            }
#pragma unroll
            for (int nn = 0; nn < 4; ++nn) {
                int node = nbase + n0 + nn;
                float dv = dinv[node];
                bf16 pk[8];
#pragma unroll
                for (int i = 0; i < 8; ++i) pk[i] = __float2bfloat16(dv * acc2[nn][i]);
                *(uint4*)&hsout[(size_t)node * 64 + c0] = *(uint4*)pk;
            }
        } else {
            // proj fused: h3 = o @ w2 (64x3); 8 lanes duplicate, c0==0 writes
            float acc3[4][3];
#pragma unroll
            for (int nn = 0; nn < 4; ++nn)
#pragma unroll
                for (int j = 0; j < 3; ++j) acc3[nn][j] = 0.f;
#pragma unroll 8
            for (int k = 0; k < 64; ++k) {
                float4 av = *(const float4*)&aT[k * 36 + n0];
                float a4[4] = {av.x, av.y, av.z, av.w};
                float w0 = s_Wn[k * 3 + 0], w1 = s_Wn[k * 3 + 1], w2v = s_Wn[k * 3 + 2];
#pragma unroll
                for (int nn = 0; nn < 4; ++nn) {
                    acc3[nn][0] = fmaf(a4[nn], w0, acc3[nn][0]);
                    acc3[nn][1] = fmaf(a4[nn], w1, acc3[nn][1]);
                    acc3[nn][2] = fmaf(a4[nn], w2v, acc3[nn][2]);
                }
            }
            if (c0 == 0) {
#pragma unroll
                for (int nn = 0; nn < 4; ++nn) {
                    int node = nbase + n0 + nn;
                    float dv = dinv[node];
                    hs3[node] = make_float4(dv * acc3[nn][0], dv * acc3[nn][1],
                                            dv * acc3[nn][2], 0.f);
                }
            }
        }
    }
}

// stage-2: aggregation (thread-per-node over CSR rowstart) + final y3 + BN stats.
__global__ void __launch_bounds__(256)
k_agg3(const float4* __restrict__ hs3, const int* __restrict__ cursor,
       const int2* __restrict__ ed2, const float* __restrict__ dinv,
       const float* __restrict__ b2, float4* __restrict__ y3,
       float* __restrict__ bnsum) {
    int v = blockIdx.x * blockDim.x + threadIdx.x;
    float y0 = 0.f, y1 = 0.f, y2 = 0.f;
    bool valid = v < N_NODES;
    if (valid) {
        int start = cursor[v];
        int end = (v + 1 < N_NODES) ? cursor[v + 1] : N_EDGES;
        float a0 = 0.f, a1 = 0.f, a2 = 0.f;
        int e = start;
        for (; e + 4 <= end; e += 4) {
            int2 c[4];
#pragma unroll
            for (int u = 0; u < 4; ++u) c[u] = ed2[e + u];
#pragma unroll
            for (int u = 0; u < 4; ++u) {
                float4 h = hs3[c[u].x];
                a0 += h.x; a1 += h.y; a2 += h.z;
            }
        }
        for (; e < end; ++e) {
            float4 h = hs3[ed2[e].x];
            a0 += h.x; a1 += h.y; a2 += h.z;
        }
        float dv = dinv[v];
        float4 hsv = hs3[v];
        y0 = dv * (a0 + 2.f * hsv.x) + b2[0];
        y1 = dv * (a1 + 2.f * hsv.y) + b2[1];
        y2 = dv * (a2 + 2.f * hsv.z) + b2[2];
        y3[v] = make_float4(y0, y1, y2, 0.f);
    }
    __shared__ float sm[256];
    float vals[6] = {y0, y1, y2, y0 * y0, y1 * y1, y2 * y2};
    for (int c = 0; c < 6; ++c) {
        sm[threadIdx.x] = valid ? vals[c] : 0.f;
        __syncthreads();
        for (int off = 128; off > 0; off >>= 1) {
            if (threadIdx.x < off) sm[threadIdx.x] += sm[threadIdx.x + off];
            __syncthreads();
        }
        if (threadIdx.x == 0) atomicAdd(&bnsum[c], sm[0]);
        __syncthreads();
    }
}

// final stage post: BN + pool(3,1) + leaky + 3x3 linear + leaky (y3 is final input)
__global__ void k_post3(const float4* __restrict__ y3, const float* __restrict__ bnsum,
                        const float* __restrict__ g, const float* __restrict__ bb,
                        const float* __restrict__ lw, const float* __restrict__ lb,
                        float* __restrict__ out) {
    int v = blockIdx.x * blockDim.x + threadIdx.x;
    if (v >= N_NODES) return;
    float inv_n = 1.0f / (float)N_NODES;
    float sc[3], sh[3];
#pragma unroll
    for (int c = 0; c < 3; ++c) {
        float mean = bnsum[c] * inv_n;
        float var = fmaxf(bnsum[3 + c] * inv_n - mean * mean, 0.f);
        sc[c] = g[c] * rsqrtf(var + 1e-5f);
        sh[c] = bb[c] - mean * sc[c];
    }
    float4 y = y3[v];
    float z0 = fmaf(y.x, sc[0], sh[0]);
    float z1 = fmaf(y.y, sc[1], sh[1]);
    float z2 = fmaf(y.z, sc[2], sh[2]);
    float p0 = fmaxf(z0, z1);
    float p1 = fmaxf(p0, z2);
    float p2 = fmaxf(z1, z2);
    float a0 = leaky(p0), a1 = leaky(p1), a2 = leaky(p2);
    float o0 = leaky(lb[0] + a0 * lw[0] + a1 * lw[1] + a2 * lw[2]);
    float o1 = leaky(lb[1] + a0 * lw[3] + a1 * lw[4] + a2 * lw[5]);
    float o2 = leaky(lb[2] + a0 * lw[6] + a1 * lw[7] + a2 * lw[8]);
    out[v * 3 + 0] = o0;
    out[v * 3 + 1] = o1;
    out[v * 3 + 2] = o2;
}

// ---------------- launcher ----------------

extern "C" void kernel_launch(void* const* d_in, const int* in_sizes, int n_in,
                              void* d_out, int out_size, void* d_ws, size_t ws_size,
                              hipStream_t stream) {
    const float* x  = (const float*)d_in[0];
    const int*   ei = (const int*)d_in[1];
    const float* w0 = (const float*)d_in[2];
    const float* b0 = (const float*)d_in[3];
    const float* g0 = (const float*)d_in[4];
    const float* bb0 = (const float*)d_in[5];
    const float* lw0 = (const float*)d_in[6];
    const float* lb0 = (const float*)d_in[7];
    const float* w1 = (const float*)d_in[8];
    const float* b1 = (const float*)d_in[9];
    const float* g1 = (const float*)d_in[10];
    const float* bb1 = (const float*)d_in[11];
    const float* lw1 = (const float*)d_in[12];
    const float* lb1 = (const float*)d_in[13];
    const float* w2 = (const float*)d_in[14];
    const float* b2 = (const float*)d_in[15];
    const float* g2 = (const float*)d_in[16];
    const float* bb2 = (const float*)d_in[17];
    const float* lw2 = (const float*)d_in[18];
    const float* lb2 = (const float*)d_in[19];
    float* out = (float*)d_out;

    // workspace layout (16B-aligned first)
    char* w = (char*)d_ws;
    float* yagg = (float*)w;       w += (size_t)N_NODES * 64 * 4;        // 20.48 MB
    int2* ed2 = (int2*)w;          w += (size_t)N_EDGES * 8;             // 10.24 MB
    unsigned int* fpairs = (unsigned int*)w; w += (size_t)NFB * FB_CAP * 4;  // 6.4 MB
    bf16* hs = (bf16*)w;           w += (size_t)N_NODES * 64 * 2;        // 10.24 MB
    float4* hs3 = (float4*)w;      w += (size_t)N_NODES * 16;            // 1.28 MB
    float4* y3 = (float4*)w;       w += (size_t)N_NODES * 16;            // 1.28 MB
    int* deg = (int*)w;            w += (size_t)N_NODES * 4;
    float* dinv = (float*)w;       w += (size_t)N_NODES * 4;
    int* cursor = (int*)w;         w += (size_t)N_NODES * 4;
    int* partial = (int*)w;        w += 512 * 4;
    float* bnsum = (float*)w;      w += 384 * 4;
    int* ctails = (int*)w;         w += NCB * 4;
    int* ftails = (int*)w;         w += NFB * 4;
    // cpairs overlays yagg (dead after k_refine, before k_h0s zero-inits yagg)
    int2* cpairs = (int2*)yagg;

    const int NB = (N_NODES + 255) / 256;  // 313

    // --- graph/CSR setup: coarse bin -> fine bin -> LDS sort -> sequential CSR write ---
    k_zero<<<NB, 256, 0, stream>>>(deg, bnsum, ctails, ftails);
    k_part<<<N_EDGES / EPB, 256, 0, stream>>>(ei, cpairs, ctails);
    k_deg_bkt<<<2048, 256, 0, stream>>>(cpairs, ctails, deg);
    k_scanA<<<NB, 256, 0, stream>>>(deg, partial, dinv);
    k_scanB<<<1, 512, 0, stream>>>(partial, NB);
    k_scanC<<<NB, 256, 0, stream>>>(deg, partial, cursor);
    k_refine<<<64 * 16, 256, 0, stream>>>(cpairs, ctails, ftails, fpairs);
    k_sortfine<<<NFB, 256, 0, stream>>>(fpairs, ftails, cursor, ed2);

    // --- stage 0 ---
    k_h0s<<<(N_NODES * 64 + 255) / 256, 256, 0, stream>>>(x, w0, dinv, hs, yagg);
    k_agg_seg<<<2500, 256, 0, stream>>>(hs, ed2, yagg);
    k_bnstats<<<640, 256, 0, stream>>>(yagg, hs, dinv, b0, bnsum);
    // ZY=true: re-zeroes yagg for stage 1 while reading it
    k_post64<1, 0, true><<<1250, 128, 0, stream>>>(yagg, hs, dinv, b0, bnsum, g0, bb0,
                                                   lw0, lb0, w1, hs, nullptr);

    // --- stage 1 ---
    k_agg_seg<<<2500, 256, 0, stream>>>(hs, ed2, yagg);
    k_bnstats<<<640, 256, 0, stream>>>(yagg, hs, dinv, b1, bnsum + 128);
    k_post64<2, 1, false><<<1250, 128, 0, stream>>>(yagg, hs, dinv, b1, bnsum + 128, g1, bb1,
                                                    lw1, lb1, w2, nullptr, hs3);

    // --- stage 2 (C=3): agg + BN stats fused ---
    k_agg3<<<NB, 256, 0, stream>>>(hs3, cursor, ed2, dinv, b2, y3, bnsum + 256);
    k_post3<<<NB, 256, 0, stream>>>(y3, bnsum + 256, g2, bb2, lw2, lb2, out);
}

// Round 18
// 422.266 us; speedup vs baseline: 1.4065x; 1.0324x over previous
//
#include <hip/hip_runtime.h>
#include <hip/hip_bf16.h>
#include <math.h>

#define N_NODES 80000
#define N_EDGES 1280000
#define CHUNK 128
#define N_CHUNKS (N_EDGES / CHUNK)  // 10000
#define NCB 64
#define CB_DIV 1250                 // coarse bucket = dst / 1250 -> 0..63
#define CB_CAP 21000                // mean 20000, +7 sigma
#define NFB 1250                    // fine bucket = dst >> 6 (64 nodes each)
#define FB_CAP 1280                 // mean 1024, +8 sigma
#define EPB 1280                    // edges per k_part block (grid 1000)

typedef __hip_bfloat16 bf16;

__device__ __forceinline__ float leaky(float x) { return x >= 0.f ? x : 0.01f * x; }

union U4 { uint4 v; bf16 h[8]; };

// ---------------- setup kernels ----------------

__global__ void k_zero(int* deg, float* bnsums, int* ctails, int* ftails) {
    int i = blockIdx.x * blockDim.x + threadIdx.x;
    if (i < N_NODES) deg[i] = 0;
    if (i < 384) bnsums[i] = 0.f;
    if (i < NCB) ctails[i] = 0;
    if (i < NFB) ftails[i] = 0;
}

// pass 1: 64-way coarse bin of (src,dst) pairs; block bulk-reserves regions.
__global__ void __launch_bounds__(256)
k_part(const int* __restrict__ ei, int2* __restrict__ cpairs,
       int* __restrict__ ctails) {
    __shared__ int cnt[NCB], off[NCB];
    int t = threadIdx.x;
    if (t < NCB) cnt[t] = 0;
    __syncthreads();
    int base = blockIdx.x * EPB;
    int2 loc[5];
#pragma unroll
    for (int u = 0; u < 5; ++u) {
        int e = base + u * 256 + t;
        int s = ei[e], d = ei[N_EDGES + e];
        loc[u] = make_int2(s, d);
        atomicAdd(&cnt[d / CB_DIV], 1);
    }
    __syncthreads();
    if (t < NCB) off[t] = atomicAdd(&ctails[t], cnt[t]);
    __syncthreads();
#pragma unroll
    for (int u = 0; u < 5; ++u) {
        int b = loc[u].y / CB_DIV;
        int pos = atomicAdd(&off[b], 1);
        cpairs[(size_t)b * CB_CAP + pos] = loc[u];
    }
}

// deg counting, bucket-pinned (atomics confined to a 5 KB dst slice per bucket).
__global__ void __launch_bounds__(256)
k_deg_bkt(const int2* __restrict__ cpairs, const int* __restrict__ ctails,
          int* __restrict__ deg) {
    int bucket = blockIdx.x & 63;
    int jb = blockIdx.x >> 6;
    int nb = gridDim.x >> 6;
    int cnt = ctails[bucket];
    const int2* lst = cpairs + (size_t)bucket * CB_CAP;
    for (int i = jb * 256 + threadIdx.x; i < cnt; i += nb * 256)
        atomicAdd(&deg[lst[i].y], 1);
}

__global__ void k_scanA(const int* __restrict__ deg, int* __restrict__ partial,
                        float* __restrict__ dinv) {
    __shared__ int s[256];
    int t = threadIdx.x;
    int i = blockIdx.x * 256 + t;
    int v = (i < N_NODES) ? deg[i] : 0;
    if (i < N_NODES) dinv[i] = rsqrtf((float)v + 2.0f);  // + self-loop weight 2
    s[t] = v;
    __syncthreads();
    for (int off = 128; off > 0; off >>= 1) {
        if (t < off) s[t] += s[t + off];
        __syncthreads();
    }
    if (t == 0) partial[blockIdx.x] = s[0];
}

__global__ void k_scanB(int* partial, int nb) {
    __shared__ int s[512];
    int t = threadIdx.x;
    int v = (t < nb) ? partial[t] : 0;
    s[t] = v;
    __syncthreads();
    for (int off = 1; off < 512; off <<= 1) {
        int x = (t >= off) ? s[t - off] : 0;
        __syncthreads();
        s[t] += x;
        __syncthreads();
    }
    if (t < nb) partial[t] = s[t] - v;  // exclusive
}

// cursor[i] = row_start(i)
__global__ void k_scanC(const int* __restrict__ deg, const int* __restrict__ partial,
                        int* __restrict__ cursor) {
    __shared__ int s[256];
    int t = threadIdx.x;
    int i = blockIdx.x * 256 + t;
    int v = (i < N_NODES) ? deg[i] : 0;
    s[t] = v;
    __syncthreads();
    for (int off = 1; off < 256; off <<= 1) {
        int x = (t >= off) ? s[t - off] : 0;
        __syncthreads();
        s[t] += x;
        __syncthreads();
    }
    if (i < N_NODES) cursor[i] = partial[blockIdx.x] + s[t] - v;
}

// pass 2: refine coarse bucket -> fine buckets of 64 nodes.
__global__ void __launch_bounds__(256)
k_refine(const int2* __restrict__ cpairs, const int* __restrict__ ctails,
         int* __restrict__ ftails, unsigned int* __restrict__ fpairs) {
    __shared__ int2 s_ed[2048];  // 16 KB strip stage
    __shared__ int cnt2[32], off2[32];
    int b = blockIdx.x & 63;
    int j = blockIdx.x >> 6;
    int t = threadIdx.x;
    int cnt = ctails[b];
    int s0 = j * 2048;
    if (s0 >= cnt) return;
    int n = min(2048, cnt - s0);
    int fb0 = (b * CB_DIV) >> 6;
    int nbins = (((b + 1) * CB_DIV - 1) >> 6) - fb0 + 1;  // <= 21
    const int2* lst = cpairs + (size_t)b * CB_CAP + s0;
    for (int i = t; i < n; i += 256) s_ed[i] = lst[i];
    if (t < 32) cnt2[t] = 0;
    __syncthreads();
    for (int i = t; i < n; i += 256)
        atomicAdd(&cnt2[(s_ed[i].y >> 6) - fb0], 1);
    __syncthreads();
    if (t < nbins && cnt2[t] > 0) off2[t] = atomicAdd(&ftails[fb0 + t], cnt2[t]);
    __syncthreads();
    for (int i = t; i < n; i += 256) {
        int2 pr = s_ed[i];
        int fbl = (pr.y >> 6) - fb0;
        int pos = atomicAdd(&off2[fbl], 1);
        fpairs[(size_t)(fb0 + fbl) * FB_CAP + pos] =
            (unsigned int)pr.x | ((unsigned int)(pr.y & 63) << 20);
    }
}

// pass 3: per-fine-bucket LDS counting sort, then SEQUENTIAL CSR write.
__global__ void __launch_bounds__(256)
k_sortfine(const unsigned int* __restrict__ fpairs, const int* __restrict__ ftails,
           const int* __restrict__ cursor, int2* __restrict__ ed2) {
    __shared__ unsigned int stage[FB_CAP];
    __shared__ int hist[64], cur[64];
    int fb = blockIdx.x;
    int t = threadIdx.x;
    int cnt = ftails[fb];
    const unsigned int* lst = fpairs + (size_t)fb * FB_CAP;
    if (t < 64) hist[t] = 0;
    __syncthreads();
    for (int i = t; i < cnt; i += 256)
        atomicAdd(&hist[lst[i] >> 20], 1);
    __syncthreads();
    if (t == 0) {
        int s = 0;
        for (int j = 0; j < 64; ++j) { cur[j] = s; s += hist[j]; }
    }
    __syncthreads();
    for (int i = t; i < cnt; i += 256) {
        unsigned int r = lst[i];
        int p = atomicAdd(&cur[r >> 20], 1);
        stage[p] = r;
    }
    __syncthreads();
    int base = cursor[fb * 64];
    int node0 = fb * 64;
    for (int i = t; i < cnt; i += 256) {
        unsigned int r = stage[i];
        ed2[base + i] = make_int2((int)(r & 0xFFFFFu), node0 + (int)(r >> 20));
    }
}

// h0 = x @ W0; hs = bf16(dinv*h0); also zero-inits yagg
__global__ void k_h0s(const float* __restrict__ x, const float* __restrict__ W0,
                      const float* __restrict__ dinv, bf16* __restrict__ hs,
                      float* __restrict__ yagg) {
    int tid = blockIdx.x * blockDim.x + threadIdx.x;
    if (tid < N_NODES * 64) {
        int v = tid >> 6, c = tid & 63;
        float x0 = x[v * 3], x1 = x[v * 3 + 1], x2 = x[v * 3 + 2];
        float h = x0 * W0[c] + x1 * W0[64 + c] + x2 * W0[128 + c];
        hs[tid] = __float2bfloat16(dinv[v] * h);
        yagg[tid] = 0.f;
    }
}

// ---------------- per-stage kernels ----------------

// segmented edge-stream aggregation over CSR-sorted records (R10 structure).
__global__ void __launch_bounds__(256)
k_agg_seg(const bf16* __restrict__ hs, const int2* __restrict__ ed2,
          float* __restrict__ yagg) {
    int lane = threadIdx.x & 63;
    int wid = (blockIdx.x * blockDim.x + threadIdx.x) >> 6;
    if (wid >= N_CHUNKS) return;
    int e = wid * CHUNK;
    int2 c[8];
#pragma unroll
    for (int u = 0; u < 8; ++u) c[u] = ed2[e + u];
    float acc = 0.f;
    int cur = __builtin_amdgcn_readfirstlane(c[0].y);
    bool lead = true;
    for (int b = 0; b < CHUNK / 8; ++b) {
        float pv[8];
#pragma unroll
        for (int u = 0; u < 8; ++u)
            pv[u] = __bfloat162float(hs[(size_t)c[u].x * 64 + lane]);
        int2 cn[8];
        if (b < CHUNK / 8 - 1) {
            int en = e + 8;
#pragma unroll
            for (int u = 0; u < 8; ++u) cn[u] = ed2[en + u];
        }
#pragma unroll
        for (int u = 0; u < 8; ++u) {
            int du = __builtin_amdgcn_readfirstlane(c[u].y);
            if (du != cur) {
                if (lead) {
                    atomicAdd(&yagg[(size_t)cur * 64 + lane], acc);
                    lead = false;
                } else {
                    yagg[(size_t)cur * 64 + lane] = acc;  // exclusive owner
                }
                acc = 0.f;
                cur = du;
            }
            acc += pv[u];
        }
        e += 8;
        if (b < CHUNK / 8 - 1) {
#pragma unroll
            for (int u = 0; u < 8; ++u) c[u] = cn[u];
        }
    }
    atomicAdd(&yagg[(size_t)cur * 64 + lane], acc);  // trailing: may straddle
}

// per-channel sum/sumsq of y_final = dinv[v]*(yagg + 2*hs_self) + bias[c]
__global__ void __launch_bounds__(256)
k_bnstats(const float* __restrict__ yagg, const bf16* __restrict__ hs,
          const float* __restrict__ dinv, const float* __restrict__ bias,
          float* __restrict__ bnsum) {
    int tid = blockIdx.x * blockDim.x + threadIdx.x;
    int stride = gridDim.x * blockDim.x;  // multiple of 64 -> lane == channel
    float bc = bias[tid & 63];
    float bs = 0.f, bss = 0.f;
    for (size_t i = tid; i < (size_t)N_NODES * 64; i += stride) {
        float comb = yagg[i] + 2.f * __bfloat162float(hs[i]);
        float yf = dinv[i >> 6] * comb + bc;
        bs += yf;
        bss += yf * yf;
    }
    __shared__ float s1[256], s2[256];
    s1[threadIdx.x] = bs;
    s2[threadIdx.x] = bss;
    __syncthreads();
    if (threadIdx.x < 64) {
        float t1 = s1[threadIdx.x] + s1[threadIdx.x + 64] + s1[threadIdx.x + 128] + s1[threadIdx.x + 192];
        float t2 = s2[threadIdx.x] + s2[threadIdx.x + 64] + s2[threadIdx.x + 128] + s2[threadIdx.x + 192];
        atomicAdd(&bnsum[threadIdx.x], t1);
        atomicAdd(&bnsum[64 + threadIdx.x], t2);
    }
}

// BN + maxpool + leaky + (a@lw.T+lb) + leaky + second matmul, register-tiled.
// 256-thread block (4 waves x 32-node subtiles = 128-node tile) sharing ONE
// bf16 weight set stored in natively-aligned uint4 LDS arrays (R17 crash fix:
// no vector-pun on bf16-typed LDS). 53,248 B -> 3 blocks x 4 waves = 12 waves/CU.
template <int P, int MODE, bool ZY>
__global__ void __launch_bounds__(256)
k_post64(float* __restrict__ yagg, const bf16* __restrict__ hs,
         const float* __restrict__ dinv, const float* __restrict__ bias,
         const float* __restrict__ bnsum,
         const float* __restrict__ g, const float* __restrict__ bb,
         const float* __restrict__ lw, const float* __restrict__ lb,
         const float* __restrict__ Wn, bf16* __restrict__ hsout,
         float4* __restrict__ hs3) {
    __shared__ float s_aT[4][64 * 36];  // per-wave activation tile (transposed), reused as oT
    __shared__ uint4 s_lwT4[64 * 8];    // lwT bf16-packed: [k][cgroup] (16B-aligned by type)
    __shared__ uint4 s_Wn4[MODE == 0 ? 64 * 8 : 1];
    __shared__ float s_Wnf[MODE == 1 ? 64 * 3 : 1];
    int t = threadIdx.x;
    int w = t >> 6, lane = t & 63;
    // weight fill: i = k*8 + cg; pack 8 channels per uint4
    for (int i = t; i < 512; i += 256) {
        int k = i >> 3, cg = i & 7;
        U4 u;
#pragma unroll
        for (int j = 0; j < 8; ++j)
            u.h[j] = __float2bfloat16(lw[(cg * 8 + j) * 64 + k]);  // lwT[k][c]
        s_lwT4[i] = u.v;
    }
    if constexpr (MODE == 0) {
        for (int i = t; i < 512; i += 256) {
            int k = i >> 3, cg = i & 7;
            U4 u;
#pragma unroll
            for (int j = 0; j < 8; ++j)
                u.h[j] = __float2bfloat16(Wn[k * 64 + cg * 8 + j]);  // Wn[k][c]
            s_Wn4[i] = u.v;
        }
    } else {
        for (int i = t; i < 64 * 3; i += 256) s_Wnf[i] = Wn[i];
    }
    float inv_n = 1.0f / (float)N_NODES;
    float mean = bnsum[lane] * inv_n;
    float var = fmaxf(bnsum[64 + lane] * inv_n - mean * mean, 0.f);
    float sc = g[lane] * rsqrtf(var + 1e-5f);
    float sh = bb[lane] - mean * sc;
    float shb = fmaf(sc, bias[lane], sh);  // folds GCN bias into BN shift
    int c0 = (lane >> 3) * 8, n0 = (lane & 7) * 4;
    int cg0 = lane >> 3;  // channel group index (c0/8)
    float lbv[8];
#pragma unroll
    for (int i = 0; i < 8; ++i) lbv[i] = lb[c0 + i];
    float* aT = s_aT[w];

    for (int tile = blockIdx.x; tile < N_NODES / 128; tile += gridDim.x) {
        int nbase = tile * 128 + w * 32;
        __syncthreads();  // covers weight-fill -> first use
#pragma unroll 4
        for (int i = 0; i < 32; ++i) {
            size_t idx = (size_t)(nbase + i) * 64 + lane;
            float comb = yagg[idx] + 2.f * __bfloat162float(hs[idx]);
            if (ZY) yagg[idx] = 0.f;  // element is dead after this read
            float z = fmaf(sc * dinv[nbase + i], comb, shb);
            float m = z;
#pragma unroll
            for (int d = 1; d <= P; ++d) {
                float up = __shfl(z, lane + d);
                float dn = __shfl(z, lane - d);
                m = fmaxf(m, (lane + d < 64) ? up : -INFINITY);
                m = fmaxf(m, (lane - d >= 0) ? dn : -INFINITY);
            }
            aT[lane * 36 + i] = leaky(m);
        }
        __syncthreads();
        // phase 2: o = leaky(a @ lw.T + lb)
        float acc[4][8];
#pragma unroll
        for (int nn = 0; nn < 4; ++nn)
#pragma unroll
            for (int i = 0; i < 8; ++i) acc[nn][i] = lbv[i];
#pragma unroll 8
        for (int k = 0; k < 64; ++k) {
            float4 av = *(const float4*)&aT[k * 36 + n0];
            U4 u; u.v = s_lwT4[k * 8 + cg0];
            float a4[4] = {av.x, av.y, av.z, av.w};
            float wv[8];
#pragma unroll
            for (int i = 0; i < 8; ++i) wv[i] = __bfloat162float(u.h[i]);
#pragma unroll
            for (int nn = 0; nn < 4; ++nn)
#pragma unroll
                for (int i = 0; i < 8; ++i) acc[nn][i] = fmaf(a4[nn], wv[i], acc[nn][i]);
        }
#pragma unroll
        for (int nn = 0; nn < 4; ++nn)
#pragma unroll
            for (int i = 0; i < 8; ++i) acc[nn][i] = leaky(acc[nn][i]);

        // write oT (aliases aT; same-wave LDS program order is safe)
#pragma unroll
        for (int i = 0; i < 8; ++i) {
            float4 ov = make_float4(acc[0][i], acc[1][i], acc[2][i], acc[3][i]);
            *(float4*)&aT[(c0 + i) * 36 + n0] = ov;
        }
        if constexpr (MODE == 0) {
            float acc2[4][8];
#pragma unroll
            for (int nn = 0; nn < 4; ++nn)
#pragma unroll
                for (int i = 0; i < 8; ++i) acc2[nn][i] = 0.f;
#pragma unroll 8
            for (int k = 0; k < 64; ++k) {
                float4 av = *(const float4*)&aT[k * 36 + n0];
                U4 u; u.v = s_Wn4[k * 8 + cg0];
                float a4[4] = {av.x, av.y, av.z, av.w};
                float wv[8];
#pragma unroll
                for (int i = 0; i < 8; ++i) wv[i] = __bfloat162float(u.h[i]);
#pragma unroll
                for (int nn = 0; nn < 4; ++nn)
#pragma unroll
                    for (int i = 0; i < 8; ++i) acc2[nn][i] = fmaf(a4[nn], wv[i], acc2[nn][i]);
            }
#pragma unroll
            for (int nn = 0; nn < 4; ++nn) {
                int node = nbase + n0 + nn;
                float dv = dinv[node];
                bf16 pk[8];
#pragma unroll
                for (int i = 0; i < 8; ++i) pk[i] = __float2bfloat16(dv * acc2[nn][i]);
                *(uint4*)&hsout[(size_t)node * 64 + c0] = *(uint4*)pk;
            }
        } else {
            // proj fused: h3 = o @ w2 (64x3); 8 lanes duplicate, c0==0 writes
            float acc3[4][3];
#pragma unroll
            for (int nn = 0; nn < 4; ++nn)
#pragma unroll
                for (int j = 0; j < 3; ++j) acc3[nn][j] = 0.f;
#pragma unroll 8
            for (int k = 0; k < 64; ++k) {
                float4 av = *(const float4*)&aT[k * 36 + n0];
                float a4[4] = {av.x, av.y, av.z, av.w};
                float w0 = s_Wnf[k * 3 + 0], w1 = s_Wnf[k * 3 + 1], w2v = s_Wnf[k * 3 + 2];
#pragma unroll
                for (int nn = 0; nn < 4; ++nn) {
                    acc3[nn][0] = fmaf(a4[nn], w0, acc3[nn][0]);
                    acc3[nn][1] = fmaf(a4[nn], w1, acc3[nn][1]);
                    acc3[nn][2] = fmaf(a4[nn], w2v, acc3[nn][2]);
                }
            }
            if (c0 == 0) {
#pragma unroll
                for (int nn = 0; nn < 4; ++nn) {
                    int node = nbase + n0 + nn;
                    float dv = dinv[node];
                    hs3[node] = make_float4(dv * acc3[nn][0], dv * acc3[nn][1],
                                            dv * acc3[nn][2], 0.f);
                }
            }
        }
    }
}

// stage-2: aggregation (thread-per-node over CSR rowstart) + final y3 + BN stats.
__global__ void __launch_bounds__(256)
k_agg3(const float4* __restrict__ hs3, const int* __restrict__ cursor,
       const int2* __restrict__ ed2, const float* __restrict__ dinv,
       const float* __restrict__ b2, float4* __restrict__ y3,
       float* __restrict__ bnsum) {
    int v = blockIdx.x * blockDim.x + threadIdx.x;
    float y0 = 0.f, y1 = 0.f, y2 = 0.f;
    bool valid = v < N_NODES;
    if (valid) {
        int start = cursor[v];
        int end = (v + 1 < N_NODES) ? cursor[v + 1] : N_EDGES;
        float a0 = 0.f, a1 = 0.f, a2 = 0.f;
        int e = start;
        for (; e + 4 <= end; e += 4) {
            int2 c[4];
#pragma unroll
            for (int u = 0; u < 4; ++u) c[u] = ed2[e + u];
#pragma unroll
            for (int u = 0; u < 4; ++u) {
                float4 h = hs3[c[u].x];
                a0 += h.x; a1 += h.y; a2 += h.z;
            }
        }
        for (; e < end; ++e) {
            float4 h = hs3[ed2[e].x];
            a0 += h.x; a1 += h.y; a2 += h.z;
        }
        float dv = dinv[v];
        float4 hsv = hs3[v];
        y0 = dv * (a0 + 2.f * hsv.x) + b2[0];
        y1 = dv * (a1 + 2.f * hsv.y) + b2[1];
        y2 = dv * (a2 + 2.f * hsv.z) + b2[2];
        y3[v] = make_float4(y0, y1, y2, 0.f);
    }
    __shared__ float sm[256];
    float vals[6] = {y0, y1, y2, y0 * y0, y1 * y1, y2 * y2};
    for (int c = 0; c < 6; ++c) {
        sm[threadIdx.x] = valid ? vals[c] : 0.f;
        __syncthreads();
        for (int off = 128; off > 0; off >>= 1) {
            if (threadIdx.x < off) sm[threadIdx.x] += sm[threadIdx.x + off];
            __syncthreads();
        }
        if (threadIdx.x == 0) atomicAdd(&bnsum[c], sm[0]);
        __syncthreads();
    }
}

// final stage post: BN + pool(3,1) + leaky + 3x3 linear + leaky
__global__ void k_post3(const float4* __restrict__ y3, const float* __restrict__ bnsum,
                        const float* __restrict__ g, const float* __restrict__ bb,
                        const float* __restrict__ lw, const float* __restrict__ lb,
                        float* __restrict__ out) {
    int v = blockIdx.x * blockDim.x + threadIdx.x;
    if (v >= N_NODES) return;
    float inv_n = 1.0f / (float)N_NODES;
    float sc[3], sh[3];
#pragma unroll
    for (int c = 0; c < 3; ++c) {
        float mean = bnsum[c] * inv_n;
        float var = fmaxf(bnsum[3 + c] * inv_n - mean * mean, 0.f);
        sc[c] = g[c] * rsqrtf(var + 1e-5f);
        sh[c] = bb[c] - mean * sc[c];
    }
    float4 y = y3[v];
    float z0 = fmaf(y.x, sc[0], sh[0]);
    float z1 = fmaf(y.y, sc[1], sh[1]);
    float z2 = fmaf(y.z, sc[2], sh[2]);
    float p0 = fmaxf(z0, z1);
    float p1 = fmaxf(p0, z2);
    float p2 = fmaxf(z1, z2);
    float a0 = leaky(p0), a1 = leaky(p1), a2 = leaky(p2);
    float o0 = leaky(lb[0] + a0 * lw[0] + a1 * lw[1] + a2 * lw[2]);
    float o1 = leaky(lb[1] + a0 * lw[3] + a1 * lw[4] + a2 * lw[5]);
    float o2 = leaky(lb[2] + a0 * lw[6] + a1 * lw[7] + a2 * lw[8]);
    out[v * 3 + 0] = o0;
    out[v * 3 + 1] = o1;
    out[v * 3 + 2] = o2;
}

// ---------------- launcher ----------------

extern "C" void kernel_launch(void* const* d_in, const int* in_sizes, int n_in,
                              void* d_out, int out_size, void* d_ws, size_t ws_size,
                              hipStream_t stream) {
    const float* x  = (const float*)d_in[0];
    const int*   ei = (const int*)d_in[1];
    const float* w0 = (const float*)d_in[2];
    const float* b0 = (const float*)d_in[3];
    const float* g0 = (const float*)d_in[4];
    const float* bb0 = (const float*)d_in[5];
    const float* lw0 = (const float*)d_in[6];
    const float* lb0 = (const float*)d_in[7];
    const float* w1 = (const float*)d_in[8];
    const float* b1 = (const float*)d_in[9];
    const float* g1 = (const float*)d_in[10];
    const float* bb1 = (const float*)d_in[11];
    const float* lw1 = (const float*)d_in[12];
    const float* lb1 = (const float*)d_in[13];
    const float* w2 = (const float*)d_in[14];
    const float* b2 = (const float*)d_in[15];
    const float* g2 = (const float*)d_in[16];
    const float* bb2 = (const float*)d_in[17];
    const float* lw2 = (const float*)d_in[18];
    const float* lb2 = (const float*)d_in[19];
    float* out = (float*)d_out;

    // workspace layout (16B-aligned first)
    char* w = (char*)d_ws;
    float* yagg = (float*)w;       w += (size_t)N_NODES * 64 * 4;        // 20.48 MB
    int2* ed2 = (int2*)w;          w += (size_t)N_EDGES * 8;             // 10.24 MB
    unsigned int* fpairs = (unsigned int*)w; w += (size_t)NFB * FB_CAP * 4;  // 6.4 MB
    bf16* hs = (bf16*)w;           w += (size_t)N_NODES * 64 * 2;        // 10.24 MB
    float4* hs3 = (float4*)w;      w += (size_t)N_NODES * 16;            // 1.28 MB
    float4* y3 = (float4*)w;       w += (size_t)N_NODES * 16;            // 1.28 MB
    int* deg = (int*)w;            w += (size_t)N_NODES * 4;
    float* dinv = (float*)w;       w += (size_t)N_NODES * 4;
    int* cursor = (int*)w;         w += (size_t)N_NODES * 4;
    int* partial = (int*)w;        w += 512 * 4;
    float* bnsum = (float*)w;      w += 384 * 4;
    int* ctails = (int*)w;         w += NCB * 4;
    int* ftails = (int*)w;         w += NFB * 4;
    // cpairs overlays yagg (dead after k_refine, before k_h0s zero-inits yagg)
    int2* cpairs = (int2*)yagg;

    const int NB = (N_NODES + 255) / 256;  // 313

    // --- graph/CSR setup: coarse bin -> fine bin -> LDS sort -> sequential CSR write ---
    k_zero<<<NB, 256, 0, stream>>>(deg, bnsum, ctails, ftails);
    k_part<<<N_EDGES / EPB, 256, 0, stream>>>(ei, cpairs, ctails);
    k_deg_bkt<<<2048, 256, 0, stream>>>(cpairs, ctails, deg);
    k_scanA<<<NB, 256, 0, stream>>>(deg, partial, dinv);
    k_scanB<<<1, 512, 0, stream>>>(partial, NB);
    k_scanC<<<NB, 256, 0, stream>>>(deg, partial, cursor);
    k_refine<<<64 * 16, 256, 0, stream>>>(cpairs, ctails, ftails, fpairs);
    k_sortfine<<<NFB, 256, 0, stream>>>(fpairs, ftails, cursor, ed2);

    // --- stage 0 ---
    k_h0s<<<(N_NODES * 64 + 255) / 256, 256, 0, stream>>>(x, w0, dinv, hs, yagg);
    k_agg_seg<<<2500, 256, 0, stream>>>(hs, ed2, yagg);
    k_bnstats<<<640, 256, 0, stream>>>(yagg, hs, dinv, b0, bnsum);
    // ZY=true: re-zeroes yagg for stage 1 while reading it
    k_post64<1, 0, true><<<625, 256, 0, stream>>>(yagg, hs, dinv, b0, bnsum, g0, bb0,
                                                  lw0, lb0, w1, hs, nullptr);

    // --- stage 1 ---
    k_agg_seg<<<2500, 256, 0, stream>>>(hs, ed2, yagg);
    k_bnstats<<<640, 256, 0, stream>>>(yagg, hs, dinv, b1, bnsum + 128);
    k_post64<2, 1, false><<<625, 256, 0, stream>>>(yagg, hs, dinv, b1, bnsum + 128, g1, bb1,
                                                   lw1, lb1, w2, nullptr, hs3);

    // --- stage 2 (C=3): agg + BN stats fused ---
    k_agg3<<<NB, 256, 0, stream>>>(hs3, cursor, ed2, dinv, b2, y3, bnsum + 256);
    k_post3<<<NB, 256, 0, stream>>>(y3, bnsum + 256, g2, bb2, lw2, lb2, out);
}

// Round 19
// 415.796 us; speedup vs baseline: 1.4284x; 1.0156x over previous
//
#include <hip/hip_runtime.h>
#include <hip/hip_bf16.h>
#include <math.h>

#define N_NODES 80000
#define N_EDGES 1280000
#define CHUNK 128
#define N_CHUNKS (N_EDGES / CHUNK)  // 10000
#define NCB 64
#define CB_DIV 1250                 // coarse bucket = dst / 1250 -> 0..63
#define CB_CAP 21000                // mean 20000, +7 sigma
#define NFB 1250                    // fine bucket = dst >> 6 (64 nodes each)
#define FB_CAP 1280                 // mean 1024, +8 sigma
#define EPB 1280                    // edges per k_part block (grid 1000)

typedef __hip_bfloat16 bf16;

__device__ __forceinline__ float leaky(float x) { return x >= 0.f ? x : 0.01f * x; }

union U4 { uint4 v; bf16 h[8]; };

// ---------------- setup kernels ----------------

__global__ void k_zero(int* deg, float* bnsums, int* ctails, int* ftails) {
    int i = blockIdx.x * blockDim.x + threadIdx.x;
    if (i < N_NODES) deg[i] = 0;
    if (i < 384) bnsums[i] = 0.f;
    if (i < NCB) ctails[i] = 0;
    if (i < NFB) ftails[i] = 0;
}

// pass 1: 64-way coarse bin of (src,dst) pairs; block bulk-reserves regions.
__global__ void __launch_bounds__(256)
k_part(const int* __restrict__ ei, int2* __restrict__ cpairs,
       int* __restrict__ ctails) {
    __shared__ int cnt[NCB], off[NCB];
    int t = threadIdx.x;
    if (t < NCB) cnt[t] = 0;
    __syncthreads();
    int base = blockIdx.x * EPB;
    int2 loc[5];
#pragma unroll
    for (int u = 0; u < 5; ++u) {
        int e = base + u * 256 + t;
        int s = ei[e], d = ei[N_EDGES + e];
        loc[u] = make_int2(s, d);
        atomicAdd(&cnt[d / CB_DIV], 1);
    }
    __syncthreads();
    if (t < NCB) off[t] = atomicAdd(&ctails[t], cnt[t]);
    __syncthreads();
#pragma unroll
    for (int u = 0; u < 5; ++u) {
        int b = loc[u].y / CB_DIV;
        int pos = atomicAdd(&off[b], 1);
        cpairs[(size_t)b * CB_CAP + pos] = loc[u];
    }
}

__global__ void k_scanA(const int* __restrict__ deg, int* __restrict__ partial,
                        float* __restrict__ dinv) {
    __shared__ int s[256];
    int t = threadIdx.x;
    int i = blockIdx.x * 256 + t;
    int v = (i < N_NODES) ? deg[i] : 0;
    if (i < N_NODES) dinv[i] = rsqrtf((float)v + 2.0f);  // + self-loop weight 2
    s[t] = v;
    __syncthreads();
    for (int off = 128; off > 0; off >>= 1) {
        if (t < off) s[t] += s[t + off];
        __syncthreads();
    }
    if (t == 0) partial[blockIdx.x] = s[0];
}

__global__ void k_scanB(int* partial, int nb) {
    __shared__ int s[512];
    int t = threadIdx.x;
    int v = (t < nb) ? partial[t] : 0;
    s[t] = v;
    __syncthreads();
    for (int off = 1; off < 512; off <<= 1) {
        int x = (t >= off) ? s[t - off] : 0;
        __syncthreads();
        s[t] += x;
        __syncthreads();
    }
    if (t < nb) partial[t] = s[t] - v;  // exclusive
}

// cursor[i] = row_start(i)
__global__ void k_scanC(const int* __restrict__ deg, const int* __restrict__ partial,
                        int* __restrict__ cursor) {
    __shared__ int s[256];
    int t = threadIdx.x;
    int i = blockIdx.x * 256 + t;
    int v = (i < N_NODES) ? deg[i] : 0;
    s[t] = v;
    __syncthreads();
    for (int off = 1; off < 256; off <<= 1) {
        int x = (t >= off) ? s[t - off] : 0;
        __syncthreads();
        s[t] += x;
        __syncthreads();
    }
    if (i < N_NODES) cursor[i] = partial[blockIdx.x] + s[t] - v;
}

// pass 2: refine coarse bucket -> fine buckets of 64 nodes. Also counts deg
// (fused from deleted k_deg_bkt — records are already staged in LDS; all 16
// strip-blocks of bucket b land on XCD b%8, so the 5 KB deg slice stays local).
__global__ void __launch_bounds__(256)
k_refine(const int2* __restrict__ cpairs, const int* __restrict__ ctails,
         int* __restrict__ ftails, unsigned int* __restrict__ fpairs,
         int* __restrict__ deg) {
    __shared__ int2 s_ed[2048];  // 16 KB strip stage
    __shared__ int cnt2[32], off2[32];
    int b = blockIdx.x & 63;
    int j = blockIdx.x >> 6;
    int t = threadIdx.x;
    int cnt = ctails[b];
    int s0 = j * 2048;
    if (s0 >= cnt) return;
    int n = min(2048, cnt - s0);
    int fb0 = (b * CB_DIV) >> 6;
    int nbins = (((b + 1) * CB_DIV - 1) >> 6) - fb0 + 1;  // <= 21
    const int2* lst = cpairs + (size_t)b * CB_CAP + s0;
    for (int i = t; i < n; i += 256) {
        int2 pr = lst[i];
        s_ed[i] = pr;
        atomicAdd(&deg[pr.y], 1);  // fused deg count (XCD-local slice)
    }
    if (t < 32) cnt2[t] = 0;
    __syncthreads();
    for (int i = t; i < n; i += 256)
        atomicAdd(&cnt2[(s_ed[i].y >> 6) - fb0], 1);
    __syncthreads();
    if (t < nbins && cnt2[t] > 0) off2[t] = atomicAdd(&ftails[fb0 + t], cnt2[t]);
    __syncthreads();
    for (int i = t; i < n; i += 256) {
        int2 pr = s_ed[i];
        int fbl = (pr.y >> 6) - fb0;
        int pos = atomicAdd(&off2[fbl], 1);
        fpairs[(size_t)(fb0 + fbl) * FB_CAP + pos] =
            (unsigned int)pr.x | ((unsigned int)(pr.y & 63) << 20);
    }
}

// pass 3: per-fine-bucket LDS counting sort, then SEQUENTIAL CSR write.
__global__ void __launch_bounds__(256)
k_sortfine(const unsigned int* __restrict__ fpairs, const int* __restrict__ ftails,
           const int* __restrict__ cursor, int2* __restrict__ ed2) {
    __shared__ unsigned int stage[FB_CAP];
    __shared__ int hist[64], cur[64];
    int fb = blockIdx.x;
    int t = threadIdx.x;
    int cnt = ftails[fb];
    const unsigned int* lst = fpairs + (size_t)fb * FB_CAP;
    if (t < 64) hist[t] = 0;
    __syncthreads();
    for (int i = t; i < cnt; i += 256)
        atomicAdd(&hist[lst[i] >> 20], 1);
    __syncthreads();
    if (t == 0) {
        int s = 0;
        for (int j = 0; j < 64; ++j) { cur[j] = s; s += hist[j]; }
    }
    __syncthreads();
    for (int i = t; i < cnt; i += 256) {
        unsigned int r = lst[i];
        int p = atomicAdd(&cur[r >> 20], 1);
        stage[p] = r;
    }
    __syncthreads();
    int base = cursor[fb * 64];
    int node0 = fb * 64;
    for (int i = t; i < cnt; i += 256) {
        unsigned int r = stage[i];
        ed2[base + i] = make_int2((int)(r & 0xFFFFFu), node0 + (int)(r >> 20));
    }
}

// h0 = x @ W0; hs = bf16(dinv*h0); also zero-inits yagg
__global__ void k_h0s(const float* __restrict__ x, const float* __restrict__ W0,
                      const float* __restrict__ dinv, bf16* __restrict__ hs,
                      float* __restrict__ yagg) {
    int tid = blockIdx.x * blockDim.x + threadIdx.x;
    if (tid < N_NODES * 64) {
        int v = tid >> 6, c = tid & 63;
        float x0 = x[v * 3], x1 = x[v * 3 + 1], x2 = x[v * 3 + 2];
        float h = x0 * W0[c] + x1 * W0[64 + c] + x2 * W0[128 + c];
        hs[tid] = __float2bfloat16(dinv[v] * h);
        yagg[tid] = 0.f;
    }
}

// ---------------- per-stage kernels ----------------

// segmented edge-stream aggregation over CSR-sorted records (R10 structure).
__global__ void __launch_bounds__(256)
k_agg_seg(const bf16* __restrict__ hs, const int2* __restrict__ ed2,
          float* __restrict__ yagg) {
    int lane = threadIdx.x & 63;
    int wid = (blockIdx.x * blockDim.x + threadIdx.x) >> 6;
    if (wid >= N_CHUNKS) return;
    int e = wid * CHUNK;
    int2 c[8];
#pragma unroll
    for (int u = 0; u < 8; ++u) c[u] = ed2[e + u];
    float acc = 0.f;
    int cur = __builtin_amdgcn_readfirstlane(c[0].y);
    bool lead = true;
    for (int b = 0; b < CHUNK / 8; ++b) {
        float pv[8];
#pragma unroll
        for (int u = 0; u < 8; ++u)
            pv[u] = __bfloat162float(hs[(size_t)c[u].x * 64 + lane]);
        int2 cn[8];
        if (b < CHUNK / 8 - 1) {
            int en = e + 8;
#pragma unroll
            for (int u = 0; u < 8; ++u) cn[u] = ed2[en + u];
        }
#pragma unroll
        for (int u = 0; u < 8; ++u) {
            int du = __builtin_amdgcn_readfirstlane(c[u].y);
            if (du != cur) {
                if (lead) {
                    atomicAdd(&yagg[(size_t)cur * 64 + lane], acc);
                    lead = false;
                } else {
                    yagg[(size_t)cur * 64 + lane] = acc;  // exclusive owner
                }
                acc = 0.f;
                cur = du;
            }
            acc += pv[u];
        }
        e += 8;
        if (b < CHUNK / 8 - 1) {
#pragma unroll
            for (int u = 0; u < 8; ++u) c[u] = cn[u];
        }
    }
    atomicAdd(&yagg[(size_t)cur * 64 + lane], acc);  // trailing: may straddle
}

// per-channel sum/sumsq of y_final = dinv[v]*(yagg + 2*hs_self) + bias[c]
__global__ void __launch_bounds__(256)
k_bnstats(const float* __restrict__ yagg, const bf16* __restrict__ hs,
          const float* __restrict__ dinv, const float* __restrict__ bias,
          float* __restrict__ bnsum) {
    int tid = blockIdx.x * blockDim.x + threadIdx.x;
    int stride = gridDim.x * blockDim.x;  // multiple of 64 -> lane == channel
    float bc = bias[tid & 63];
    float bs = 0.f, bss = 0.f;
    for (size_t i = tid; i < (size_t)N_NODES * 64; i += stride) {
        float comb = yagg[i] + 2.f * __bfloat162float(hs[i]);
        float yf = dinv[i >> 6] * comb + bc;
        bs += yf;
        bss += yf * yf;
    }
    __shared__ float s1[256], s2[256];
    s1[threadIdx.x] = bs;
    s2[threadIdx.x] = bss;
    __syncthreads();
    if (threadIdx.x < 64) {
        float t1 = s1[threadIdx.x] + s1[threadIdx.x + 64] + s1[threadIdx.x + 128] + s1[threadIdx.x + 192];
        float t2 = s2[threadIdx.x] + s2[threadIdx.x + 64] + s2[threadIdx.x + 128] + s2[threadIdx.x + 192];
        atomicAdd(&bnsum[threadIdx.x], t1);
        atomicAdd(&bnsum[64 + threadIdx.x], t2);
    }
}

// BN + maxpool + leaky + (a@lw.T+lb) + leaky + second matmul, register-tiled.
// 256-thread block (4 waves x 32-node subtiles) sharing ONE bf16 weight set
// in natively-aligned uint4 LDS. 53,248 B -> 3 blocks x 4 waves = 12 waves/CU.
template <int P, int MODE, bool ZY>
__global__ void __launch_bounds__(256)
k_post64(float* __restrict__ yagg, const bf16* __restrict__ hs,
         const float* __restrict__ dinv, const float* __restrict__ bias,
         const float* __restrict__ bnsum,
         const float* __restrict__ g, const float* __restrict__ bb,
         const float* __restrict__ lw, const float* __restrict__ lb,
         const float* __restrict__ Wn, bf16* __restrict__ hsout,
         float4* __restrict__ hs3) {
    __shared__ float s_aT[4][64 * 36];  // per-wave activation tile (transposed), reused as oT
    __shared__ uint4 s_lwT4[64 * 8];    // lwT bf16-packed: [k][cgroup]
    __shared__ uint4 s_Wn4[MODE == 0 ? 64 * 8 : 1];
    __shared__ float s_Wnf[MODE == 1 ? 64 * 3 : 1];
    int t = threadIdx.x;
    int w = t >> 6, lane = t & 63;
    for (int i = t; i < 512; i += 256) {
        int k = i >> 3, cg = i & 7;
        U4 u;
#pragma unroll
        for (int j = 0; j < 8; ++j)
            u.h[j] = __float2bfloat16(lw[(cg * 8 + j) * 64 + k]);  // lwT[k][c]
        s_lwT4[i] = u.v;
    }
    if constexpr (MODE == 0) {
        for (int i = t; i < 512; i += 256) {
            int k = i >> 3, cg = i & 7;
            U4 u;
#pragma unroll
            for (int j = 0; j < 8; ++j)
                u.h[j] = __float2bfloat16(Wn[k * 64 + cg * 8 + j]);  // Wn[k][c]
            s_Wn4[i] = u.v;
        }
    } else {
        for (int i = t; i < 64 * 3; i += 256) s_Wnf[i] = Wn[i];
    }
    float inv_n = 1.0f / (float)N_NODES;
    float mean = bnsum[lane] * inv_n;
    float var = fmaxf(bnsum[64 + lane] * inv_n - mean * mean, 0.f);
    float sc = g[lane] * rsqrtf(var + 1e-5f);
    float sh = bb[lane] - mean * sc;
    float shb = fmaf(sc, bias[lane], sh);  // folds GCN bias into BN shift
    int c0 = (lane >> 3) * 8, n0 = (lane & 7) * 4;
    int cg0 = lane >> 3;
    float lbv[8];
#pragma unroll
    for (int i = 0; i < 8; ++i) lbv[i] = lb[c0 + i];
    float* aT = s_aT[w];

    for (int tile = blockIdx.x; tile < N_NODES / 128; tile += gridDim.x) {
        int nbase = tile * 128 + w * 32;
        __syncthreads();  // covers weight-fill -> first use
#pragma unroll 4
        for (int i = 0; i < 32; ++i) {
            size_t idx = (size_t)(nbase + i) * 64 + lane;
            float comb = yagg[idx] + 2.f * __bfloat162float(hs[idx]);
            if (ZY) yagg[idx] = 0.f;  // element is dead after this read
            float z = fmaf(sc * dinv[nbase + i], comb, shb);
            float m = z;
#pragma unroll
            for (int d = 1; d <= P; ++d) {
                float up = __shfl(z, lane + d);
                float dn = __shfl(z, lane - d);
                m = fmaxf(m, (lane + d < 64) ? up : -INFINITY);
                m = fmaxf(m, (lane - d >= 0) ? dn : -INFINITY);
            }
            aT[lane * 36 + i] = leaky(m);
        }
        __syncthreads();
        // phase 2: o = leaky(a @ lw.T + lb)
        float acc[4][8];
#pragma unroll
        for (int nn = 0; nn < 4; ++nn)
#pragma unroll
            for (int i = 0; i < 8; ++i) acc[nn][i] = lbv[i];
#pragma unroll 8
        for (int k = 0; k < 64; ++k) {
            float4 av = *(const float4*)&aT[k * 36 + n0];
            U4 u; u.v = s_lwT4[k * 8 + cg0];
            float a4[4] = {av.x, av.y, av.z, av.w};
            float wv[8];
#pragma unroll
            for (int i = 0; i < 8; ++i) wv[i] = __bfloat162float(u.h[i]);
#pragma unroll
            for (int nn = 0; nn < 4; ++nn)
#pragma unroll
                for (int i = 0; i < 8; ++i) acc[nn][i] = fmaf(a4[nn], wv[i], acc[nn][i]);
        }
#pragma unroll
        for (int nn = 0; nn < 4; ++nn)
#pragma unroll
            for (int i = 0; i < 8; ++i) acc[nn][i] = leaky(acc[nn][i]);

        // write oT (aliases aT; same-wave LDS program order is safe)
#pragma unroll
        for (int i = 0; i < 8; ++i) {
            float4 ov = make_float4(acc[0][i], acc[1][i], acc[2][i], acc[3][i]);
            *(float4*)&aT[(c0 + i) * 36 + n0] = ov;
        }
        if constexpr (MODE == 0) {
            float acc2[4][8];
#pragma unroll
            for (int nn = 0; nn < 4; ++nn)
#pragma unroll
                for (int i = 0; i < 8; ++i) acc2[nn][i] = 0.f;
#pragma unroll 8
            for (int k = 0; k < 64; ++k) {
                float4 av = *(const float4*)&aT[k * 36 + n0];
                U4 u; u.v = s_Wn4[k * 8 + cg0];
                float a4[4] = {av.x, av.y, av.z, av.w};
                float wv[8];
#pragma unroll
                for (int i = 0; i < 8; ++i) wv[i] = __bfloat162float(u.h[i]);
#pragma unroll
                for (int nn = 0; nn < 4; ++nn)
#pragma unroll
                    for (int i = 0; i < 8; ++i) acc2[nn][i] = fmaf(a4[nn], wv[i], acc2[nn][i]);
            }
#pragma unroll
            for (int nn = 0; nn < 4; ++nn) {
                int node = nbase + n0 + nn;
                float dv = dinv[node];
                bf16 pk[8];
#pragma unroll
                for (int i = 0; i < 8; ++i) pk[i] = __float2bfloat16(dv * acc2[nn][i]);
                *(uint4*)&hsout[(size_t)node * 64 + c0] = *(uint4*)pk;
            }
        } else {
            // proj fused: h3 = o @ w2 (64x3); 8 lanes duplicate, c0==0 writes
            float acc3[4][3];
#pragma unroll
            for (int nn = 0; nn < 4; ++nn)
#pragma unroll
                for (int j = 0; j < 3; ++j) acc3[nn][j] = 0.f;
#pragma unroll 8
            for (int k = 0; k < 64; ++k) {
                float4 av = *(const float4*)&aT[k * 36 + n0];
                float a4[4] = {av.x, av.y, av.z, av.w};
                float w0 = s_Wnf[k * 3 + 0], w1 = s_Wnf[k * 3 + 1], w2v = s_Wnf[k * 3 + 2];
#pragma unroll
                for (int nn = 0; nn < 4; ++nn) {
                    acc3[nn][0] = fmaf(a4[nn], w0, acc3[nn][0]);
                    acc3[nn][1] = fmaf(a4[nn], w1, acc3[nn][1]);
                    acc3[nn][2] = fmaf(a4[nn], w2v, acc3[nn][2]);
                }
            }
            if (c0 == 0) {
#pragma unroll
                for (int nn = 0; nn < 4; ++nn) {
                    int node = nbase + n0 + nn;
                    float dv = dinv[node];
                    hs3[node] = make_float4(dv * acc3[nn][0], dv * acc3[nn][1],
                                            dv * acc3[nn][2], 0.f);
                }
            }
        }
    }
}

// stage-2: aggregation (thread-per-node over CSR rowstart) + final y3 + BN stats.
__global__ void __launch_bounds__(256)
k_agg3(const float4* __restrict__ hs3, const int* __restrict__ cursor,
       const int2* __restrict__ ed2, const float* __restrict__ dinv,
       const float* __restrict__ b2, float4* __restrict__ y3,
       float* __restrict__ bnsum) {
    int v = blockIdx.x * blockDim.x + threadIdx.x;
    float y0 = 0.f, y1 = 0.f, y2 = 0.f;
    bool valid = v < N_NODES;
    if (valid) {
        int start = cursor[v];
        int end = (v + 1 < N_NODES) ? cursor[v + 1] : N_EDGES;
        float a0 = 0.f, a1 = 0.f, a2 = 0.f;
        int e = start;
        for (; e + 4 <= end; e += 4) {
            int2 c[4];
#pragma unroll
            for (int u = 0; u < 4; ++u) c[u] = ed2[e + u];
#pragma unroll
            for (int u = 0; u < 4; ++u) {
                float4 h = hs3[c[u].x];
                a0 += h.x; a1 += h.y; a2 += h.z;
            }
        }
        for (; e < end; ++e) {
            float4 h = hs3[ed2[e].x];
            a0 += h.x; a1 += h.y; a2 += h.z;
        }
        float dv = dinv[v];
        float4 hsv = hs3[v];
        y0 = dv * (a0 + 2.f * hsv.x) + b2[0];
        y1 = dv * (a1 + 2.f * hsv.y) + b2[1];
        y2 = dv * (a2 + 2.f * hsv.z) + b2[2];
        y3[v] = make_float4(y0, y1, y2, 0.f);
    }
    __shared__ float sm[256];
    float vals[6] = {y0, y1, y2, y0 * y0, y1 * y1, y2 * y2};
    for (int c = 0; c < 6; ++c) {
        sm[threadIdx.x] = valid ? vals[c] : 0.f;
        __syncthreads();
        for (int off = 128; off > 0; off >>= 1) {
            if (threadIdx.x < off) sm[threadIdx.x] += sm[threadIdx.x + off];
            __syncthreads();
        }
        if (threadIdx.x == 0) atomicAdd(&bnsum[c], sm[0]);
        __syncthreads();
    }
}

// final stage post: BN + pool(3,1) + leaky + 3x3 linear + leaky
__global__ void k_post3(const float4* __restrict__ y3, const float* __restrict__ bnsum,
                        const float* __restrict__ g, const float* __restrict__ bb,
                        const float* __restrict__ lw, const float* __restrict__ lb,
                        float* __restrict__ out) {
    int v = blockIdx.x * blockDim.x + threadIdx.x;
    if (v >= N_NODES) return;
    float inv_n = 1.0f / (float)N_NODES;
    float sc[3], sh[3];
#pragma unroll
    for (int c = 0; c < 3; ++c) {
        float mean = bnsum[c] * inv_n;
        float var = fmaxf(bnsum[3 + c] * inv_n - mean * mean, 0.f);
        sc[c] = g[c] * rsqrtf(var + 1e-5f);
        sh[c] = bb[c] - mean * sc[c];
    }
    float4 y = y3[v];
    float z0 = fmaf(y.x, sc[0], sh[0]);
    float z1 = fmaf(y.y, sc[1], sh[1]);
    float z2 = fmaf(y.z, sc[2], sh[2]);
    float p0 = fmaxf(z0, z1);
    float p1 = fmaxf(p0, z2);
    float p2 = fmaxf(z1, z2);
    float a0 = leaky(p0), a1 = leaky(p1), a2 = leaky(p2);
    float o0 = leaky(lb[0] + a0 * lw[0] + a1 * lw[1] + a2 * lw[2]);
    float o1 = leaky(lb[1] + a0 * lw[3] + a1 * lw[4] + a2 * lw[5]);
    float o2 = leaky(lb[2] + a0 * lw[6] + a1 * lw[7] + a2 * lw[8]);
    out[v * 3 + 0] = o0;
    out[v * 3 + 1] = o1;
    out[v * 3 + 2] = o2;
}

// ---------------- launcher ----------------

extern "C" void kernel_launch(void* const* d_in, const int* in_sizes, int n_in,
                              void* d_out, int out_size, void* d_ws, size_t ws_size,
                              hipStream_t stream) {
    const float* x  = (const float*)d_in[0];
    const int*   ei = (const int*)d_in[1];
    const float* w0 = (const float*)d_in[2];
    const float* b0 = (const float*)d_in[3];
    const float* g0 = (const float*)d_in[4];
    const float* bb0 = (const float*)d_in[5];
    const float* lw0 = (const float*)d_in[6];
    const float* lb0 = (const float*)d_in[7];
    const float* w1 = (const float*)d_in[8];
    const float* b1 = (const float*)d_in[9];
    const float* g1 = (const float*)d_in[10];
    const float* bb1 = (const float*)d_in[11];
    const float* lw1 = (const float*)d_in[12];
    const float* lb1 = (const float*)d_in[13];
    const float* w2 = (const float*)d_in[14];
    const float* b2 = (const float*)d_in[15];
    const float* g2 = (const float*)d_in[16];
    const float* bb2 = (const float*)d_in[17];
    const float* lw2 = (const float*)d_in[18];
    const float* lb2 = (const float*)d_in[19];
    float* out = (float*)d_out;

    // workspace layout (16B-aligned first)
    char* w = (char*)d_ws;
    float* yagg = (float*)w;       w += (size_t)N_NODES * 64 * 4;        // 20.48 MB
    int2* ed2 = (int2*)w;          w += (size_t)N_EDGES * 8;             // 10.24 MB
    unsigned int* fpairs = (unsigned int*)w; w += (size_t)NFB * FB_CAP * 4;  // 6.4 MB
    bf16* hs = (bf16*)w;           w += (size_t)N_NODES * 64 * 2;        // 10.24 MB
    float4* hs3 = (float4*)w;      w += (size_t)N_NODES * 16;            // 1.28 MB
    float4* y3 = (float4*)w;       w += (size_t)N_NODES * 16;            // 1.28 MB
    int* deg = (int*)w;            w += (size_t)N_NODES * 4;
    float* dinv = (float*)w;       w += (size_t)N_NODES * 4;
    int* cursor = (int*)w;         w += (size_t)N_NODES * 4;
    int* partial = (int*)w;        w += 512 * 4;
    float* bnsum = (float*)w;      w += 384 * 4;
    int* ctails = (int*)w;         w += NCB * 4;
    int* ftails = (int*)w;         w += NFB * 4;
    // cpairs overlays yagg (dead after k_refine, before k_h0s zero-inits yagg)
    int2* cpairs = (int2*)yagg;

    const int NB = (N_NODES + 255) / 256;  // 313

    // --- graph/CSR setup: coarse bin -> refine(+deg) -> scans -> LDS sort -> CSR ---
    k_zero<<<NB, 256, 0, stream>>>(deg, bnsum, ctails, ftails);
    k_part<<<N_EDGES / EPB, 256, 0, stream>>>(ei, cpairs, ctails);
    k_refine<<<64 * 16, 256, 0, stream>>>(cpairs, ctails, ftails, fpairs, deg);
    k_scanA<<<NB, 256, 0, stream>>>(deg, partial, dinv);
    k_scanB<<<1, 512, 0, stream>>>(partial, NB);
    k_scanC<<<NB, 256, 0, stream>>>(deg, partial, cursor);
    k_sortfine<<<NFB, 256, 0, stream>>>(fpairs, ftails, cursor, ed2);

    // --- stage 0 ---
    k_h0s<<<(N_NODES * 64 + 255) / 256, 256, 0, stream>>>(x, w0, dinv, hs, yagg);
    k_agg_seg<<<2500, 256, 0, stream>>>(hs, ed2, yagg);
    k_bnstats<<<640, 256, 0, stream>>>(yagg, hs, dinv, b0, bnsum);
    // ZY=true: re-zeroes yagg for stage 1 while reading it
    k_post64<1, 0, true><<<625, 256, 0, stream>>>(yagg, hs, dinv, b0, bnsum, g0, bb0,
                                                  lw0, lb0, w1, hs, nullptr);

    // --- stage 1 ---
    k_agg_seg<<<2500, 256, 0, stream>>>(hs, ed2, yagg);
    k_bnstats<<<640, 256, 0, stream>>>(yagg, hs, dinv, b1, bnsum + 128);
    k_post64<2, 1, false><<<625, 256, 0, stream>>>(yagg, hs, dinv, b1, bnsum + 128, g1, bb1,
                                                   lw1, lb1, w2, nullptr, hs3);

    // --- stage 2 (C=3): agg + BN stats fused ---
    k_agg3<<<NB, 256, 0, stream>>>(hs3, cursor, ed2, dinv, b2, y3, bnsum + 256);
    k_post3<<<NB, 256, 0, stream>>>(y3, bnsum + 256, g2, bb2, lw2, lb2, out);
}